// Round 10
// baseline (5992.942 us; speedup 1.0000x reference)
//
#include <hip/hip_runtime.h>

// ---------------------------------------------------------------------------
// Fused decoder R10: B=8192 x 40 steps, 1 WG (1024 thr, 16 waves) per 32 rows,
// grid=256. Weights stream global->regs->LDS through a 2x32KB ring
// (52 slices/step: 44 gates @32x32x16 + 8 tail @16x16x32). Reg-staged
// (plain loads + ds_write; compiler emits exact vmcnt waits), lgkmcnt-only
// barriers keep staging loads in flight across compute. No global_load_lds,
// no manual vmcnt counting (R8/R9 crash mechanisms removed).
// ---------------------------------------------------------------------------

#define BDIM  8192
#define HDIM  256
#define FDIM  128
#define ZDIM  64
#define TDIM  43
#define STEPS 40

typedef __attribute__((ext_vector_type(8)))  __bf16 bf16x8;
typedef __attribute__((ext_vector_type(4)))  float  f32x4;
typedef __attribute__((ext_vector_type(16))) float  f32x16;

// act: 32 rows x 1344 bf16 cols, stride 2704B (676 dw == 4 mod 32), +16B/8rows
#define ACT_STRIDE 2704
#define C_Z   0      // z (64)
#define C_HI  64     // h_i (256, permanent)
#define C_Y0  320    // y parity 0 (128)
#define C_Y1  448    // y parity 1 (128)
#define C_H   576    // h single buffer (256)
#define C_C   832    // c_new (256)
#define C_T0  1088   // y1 (128) — overlaid by hzp
#define C_T1  1216   // y2 (128) — overlaid by hz
#define C_HZP C_T0
#define C_HZ  C_T1

// ws BYTE offsets (streamed slices) / ELEM offsets (register-loaded smalls)
#define WB_G    0u         // 44 slices x 32KB (gates K=704: z|h_i|yp|h)
#define WB_W1A  1441792u
#define WB_W1B  1474560u
#define WB_W2   1507328u
#define WB_W3   1540096u
#define WB_W7SA 1572864u   // W7S kt0-7 (c-part, 32KB)
#define WB_W7SB 1605632u   // W7S kt8-11 (yp-part, 16KB)
#define WB_W4C  1622016u   // W4S kt0-7 (c-part, 32KB)
#define WB_W4YP 1654784u   // W4S kt8-15 (y|yp, 32KB)
#define PW_W4H  843776u
#define PW_W7H  860160u
#define PW_W5   876544u
#define PW_W6   880640u
#define PW_W8   884736u
#define PW_W9   888832u

__device__ __forceinline__ int act_off(int row, int col) {
  return row * ACT_STRIDE + ((row >> 3) << 4) + (col << 1);
}
__device__ __forceinline__ f32x16 mfma32(bf16x8 a, bf16x8 b, f32x16 c) {
  return __builtin_amdgcn_mfma_f32_32x32x16_bf16(a, b, c, 0, 0, 0);
}
__device__ __forceinline__ f32x4 mfma16(bf16x8 a, bf16x8 b, f32x4 c) {
  return __builtin_amdgcn_mfma_f32_16x16x32_bf16(a, b, c, 0, 0, 0);
}
__device__ __forceinline__ float sigm(float x) { return 1.f / (1.f + __expf(-x)); }
__device__ __forceinline__ float tanh_f(float x) {
  float t = __expf(-2.f * fabsf(x));
  float r = (1.f - t) / (1.f + t);
  return x < 0.f ? -r : r;
}
// lgkmcnt-only barrier: staging global loads stay in flight across it.
__device__ __forceinline__ void wg_barrier() {
  asm volatile("s_waitcnt lgkmcnt(0)" ::: "memory");
  __builtin_amdgcn_s_barrier();
  __builtin_amdgcn_sched_barrier(0);
}
// reg-staged slice: 1024 threads x 32B (full) or 16B (half)
struct StageReg { uint4 a, b; };
__device__ __forceinline__ void issueS(StageReg& st, const unsigned char* src, int tid,
                                       bool half) {
  st.a = *(const uint4*)(src + tid * 16);
  if (!half) st.b = *(const uint4*)(src + 16384 + tid * 16);
}
__device__ __forceinline__ void writeS(const StageReg& st, unsigned char* ring, int par,
                                       int tid, bool half) {
  *(uint4*)(ring + par * 32768 + tid * 16) = st.a;
  if (!half) *(uint4*)(ring + par * 32768 + 16384 + tid * 16) = st.b;
}
__device__ __forceinline__ bf16x8 aread16(const unsigned char* a, int mt, int col,
                                          int lane) {
  return *(const bf16x8*)(a + act_off(mt * 16 + (lane & 15), col + ((lane >> 4) << 3)));
}
__device__ __forceinline__ bf16x8 aread32(const unsigned char* a, int col, int lane) {
  return *(const bf16x8*)(a + act_off(lane & 31, col + ((lane >> 5) << 3)));
}
__device__ __forceinline__ void st16(unsigned char* a, int col, int mt, int rsub,
                                     f32x4 v, float bv) {
#pragma unroll
  for (int r = 0; r < 4; ++r)
    *(__bf16*)(a + act_off(mt * 16 + rsub + r, col)) = (__bf16)fmaxf(v[r] + bv, 0.f);
}

// ---------------------------------------------------------------------------
// Packers (layouts as R8/R9; the small nt-major one is R3-R7-proven)
// ---------------------------------------------------------------------------
__global__ __launch_bounds__(256) void pack_gates(const float* __restrict__ Wx,
                                                  const float* __restrict__ Wh,
                                                  __bf16* __restrict__ dst) {
  int f = blockIdx.x * 256 + threadIdx.x;
  if (f >= 44 * 32 * 64) return;
  int lane = f & 63, t = f >> 6, ct = t & 31, s = t >> 5;
  int k0 = s * 16 + ((lane >> 5) << 3);
  int col = (ct << 5) + (lane & 31);
  bf16x8 v;
#pragma unroll
  for (int j = 0; j < 8; ++j) {
    int k = k0 + j;
    v[j] = (__bf16)((k < 448) ? Wx[(size_t)k * 1024 + col]
                              : Wh[(size_t)(k - 448) * 1024 + col]);
  }
  *(bf16x8*)(dst + (size_t)f * 8) = v;
}
__global__ __launch_bounds__(256) void pack_tail(const float* __restrict__ src, int row0,
                                                 int K, int N, __bf16* __restrict__ dst) {
  int NT = N >> 4, KT = K >> 5;
  int f = blockIdx.x * 256 + threadIdx.x;
  if (f >= KT * NT * 64) return;
  int lane = f & 63, t = f >> 6, nt = t % NT, kt = t / NT;
  int k0 = row0 + kt * 32 + ((lane >> 4) << 3);
  int col = (nt << 4) + (lane & 15);
  bf16x8 v;
#pragma unroll
  for (int j = 0; j < 8; ++j) v[j] = (__bf16)src[(size_t)(k0 + j) * N + col];
  *(bf16x8*)(dst + (size_t)f * 8) = v;
}
struct PSeg { const float* p; int row0; int len; };
__global__ __launch_bounds__(256) void pack_w(PSeg s0, int K, int N,
                                              __bf16* __restrict__ dst) {
  int KT = K >> 5;
  int total = KT * (N >> 4) * 64;
  int f = blockIdx.x * 256 + threadIdx.x;
  if (f >= total) return;
  int lane = f & 63, tile = f >> 6, kt = tile % KT, nt = tile / KT;
  int k0 = kt * 32 + ((lane >> 4) << 3);
  int n = (nt << 4) + (lane & 15);
  bf16x8 v;
#pragma unroll
  for (int j = 0; j < 8; ++j)
    v[j] = (__bf16)s0.p[(size_t)(s0.row0 + k0 + j) * N + n];
  *(bf16x8*)(dst + (size_t)f * 8) = v;
}

struct Params {
  const float *h_i, *input_t, *eps_inf, *eps_prior;
  const float *b_lstm, *b1, *b2, *b3, *b4, *b5, *b6, *b7, *b8, *b9;
  const float *alpha, *beta, *mu0;
  const __bf16* wpack;
  float* out;
};

__global__ __launch_bounds__(1024, 4) void decoder_main(Params p) {
  __shared__ __align__(16) unsigned char act[86592];
  __shared__ __align__(16) unsigned char ring[65536];
  __shared__ float inten[STEPS * 32];

  const int tid = threadIdx.x;
  const int w = tid >> 6;
  const int lane = tid & 63;
  const int ln16 = lane & 15;
  const int nl = lane & 31;
  const int rsub = (lane >> 4) << 2;
  const int r0 = blockIdx.x * 32;
  const unsigned char* wsb = (const unsigned char*)p.wpack;

  for (int i = tid; i < 86592 / 4; i += 1024) ((unsigned int*)act)[i] = 0u;
  __syncthreads();
  for (int i = tid; i < 32 * 256; i += 1024) {
    int row = i >> 8, col = i & 255;
    *(__bf16*)(act + act_off(row, C_HI + col)) =
        (__bf16)p.h_i[(size_t)(r0 + row) * HDIM + col];
  }
  {
    float ab = p.alpha[0] * p.beta[0], mu = p.mu0[0];
    for (int t = tid; t < 32 * STEPS; t += 1024) {
      int row = t & 31, j = t >> 5;
      const float* tp = p.input_t + (size_t)(r0 + row) * TDIM;
      float tc = tp[j + 3];
      float s = 0.f;
      for (int idx = 0; idx < j + 3; ++idx) s += __expf(tp[idx] - tc);
      inten[j * 32 + row] = mu + ab * s;
    }
  }
  __syncthreads();

  const __bf16* W = p.wpack;
  const bf16x8* w4h = (const bf16x8*)(W + PW_W4H);
  const bf16x8* w7h = (const bf16x8*)(W + PW_W7H);
  const bf16x8* w5p = (const bf16x8*)(W + PW_W5);
  const bf16x8* w6p = (const bf16x8*)(W + PW_W6);
  const bf16x8* w8p = (const bf16x8*)(W + PW_W8);
  const bf16x8* w9p = (const bf16x8*)(W + PW_W9);

  const int n2 = (w & 7) & 3, m2 = ((w & 7) >> 2) & 1;
  // startup folds: waves 8-15 compute h_i@w4h+b4, h_i@w7h+b7 -> regs
  f32x4 b4f = {}, b7f = {};
  if (w >= 8) {
    f32x4 v4 = {}, v7 = {};
#pragma unroll
    for (int kt = 0; kt < 8; ++kt) {
      bf16x8 a = aread16(act, m2, C_HI + kt * 32, lane);
      v4 = mfma16(a, w4h[(size_t)(n2 * 8 + kt) * 64 + lane], v4);
      v7 = mfma16(a, w7h[(size_t)(n2 * 8 + kt) * 64 + lane], v7);
    }
    float b4v = p.b4[n2 * 16 + ln16], b7v = p.b7[n2 * 16 + ln16];
#pragma unroll
    for (int r = 0; r < 4; ++r) { b4f[r] = v4[r] + b4v; b7f[r] = v7[r] + b7v; }
  }
  // bias hoists
  float bA = 0, bB = 0;
  float bi = 0, bf2 = 0, bg = 0, bo = 0, bv1 = 0, bv2 = 0, bv3 = 0;
  if (w < 8) {
    bA = p.b5[n2 * 16 + ln16];
    bB = p.b6[n2 * 16 + ln16];
    bi = p.b_lstm[w * 32 + nl];
    bf2 = p.b_lstm[256 + w * 32 + nl];
    bg = p.b_lstm[512 + w * 32 + nl];
    bo = p.b_lstm[768 + w * 32 + nl];
    bv1 = p.b1[w * 16 + ln16];
    bv2 = p.b2[w * 16 + ln16];
    bv3 = p.b3[w * 16 + ln16];
  } else {
    bA = p.b8[n2 * 16 + ln16];
    bB = p.b9[n2 * 16 + ln16];
  }
  f32x16 c_st = {};
  __syncthreads();

  float* outy = p.out;
  float* outm = p.out + (size_t)BDIM * STEPS * FDIM;
  float* outl = outm + (size_t)BDIM * STEPS * ZDIM;
  float* outz = outl + (size_t)BDIM * STEPS * ZDIM;
  float* outzp = outz + (size_t)BDIM * STEPS * ZDIM;

  StageReg st;
  issueS(st, wsb + WB_G, tid, false);  // slice 0 of step 0

  for (int j = 0; j < STEPS; ++j) {
    const int yW = (j & 1) ? C_Y1 : C_Y0, yR = (j & 1) ? C_Y0 : C_Y1;

    // ===== gates: 44 slices (par = k&1), waves 0-7 consume =====
    f32x16 a0 = {}, a1 = {}, a2 = {}, a3 = {};
    for (int k = 0; k < 44; ++k) {
      writeS(st, ring, k & 1, tid, false);
      const unsigned char* nxt =
          (k < 43) ? (wsb + WB_G + (unsigned)(k + 1) * 32768u) : (wsb + WB_W1A);
      issueS(st, nxt, tid, false);
      wg_barrier();
      if (w < 8) {
        const bf16x8* rb = (const bf16x8*)(ring + (k & 1) * 32768);
        int colb = (k < 4) ? (C_Z + k * 16)
                           : (k < 20) ? (C_HI + (k - 4) * 16)
                                      : (k < 28) ? (yR + (k - 20) * 16)
                                                 : (C_H + (k - 28) * 16);
        bf16x8 a = aread32(act, colb, lane);
        a0 = mfma32(a, rb[(0 * 8 + w) * 64 + lane], a0);
        a1 = mfma32(a, rb[(1 * 8 + w) * 64 + lane], a1);
        a2 = mfma32(a, rb[(2 * 8 + w) * 64 + lane], a2);
        a3 = mfma32(a, rb[(3 * 8 + w) * 64 + lane], a3);
      }
      wg_barrier();
    }

    // ===== LSTM pointwise (waves 0-7) -> C_C, C_H =====
    if (w < 8) {
#pragma unroll
      for (int r = 0; r < 16; ++r) {
        int row = (r & 3) + ((r >> 2) << 3) + ((lane >> 5) << 2);
        float ig = sigm(a0[r] + bi);
        float fg = sigm(a1[r] + bf2);
        float gg = tanh_f(a2[r] + bg);
        float og = sigm(a3[r] + bo);
        float cn = fg * c_st[r] + ig * gg;
        float hn = og * tanh_f(cn);
        c_st[r] = inten[j * 32 + row] * cn;
        *(__bf16*)(act + act_off(row, C_C + w * 32 + nl)) = (__bf16)cn;
        *(__bf16*)(act + act_off(row, C_H + w * 32 + nl)) = (__bf16)hn;
      }
    }

    // ===== s44: W1A (par0) — y1 part1 =====
    writeS(st, ring, 0, tid, false);
    issueS(st, wsb + WB_W1B, tid, false);
    wg_barrier();
    f32x4 y1a = {}, y1b = {};
    if (w < 8) {
      const bf16x8* rb = (const bf16x8*)(ring);
#pragma unroll
      for (int ktl = 0; ktl < 4; ++ktl) {
        bf16x8 b = rb[(ktl * 8 + w) * 64 + lane];
        y1a = mfma16(aread16(act, 0, C_H + ktl * 32, lane), b, y1a);
        y1b = mfma16(aread16(act, 1, C_H + ktl * 32, lane), b, y1b);
      }
    }
    wg_barrier();

    // ===== s45: W1B (par1) — y1 finish -> C_T0 =====
    writeS(st, ring, 1, tid, false);
    issueS(st, wsb + WB_W2, tid, false);
    wg_barrier();
    if (w < 8) {
      const bf16x8* rb = (const bf16x8*)(ring + 32768);
#pragma unroll
      for (int ktl = 0; ktl < 4; ++ktl) {
        bf16x8 b = rb[(ktl * 8 + w) * 64 + lane];
        y1a = mfma16(aread16(act, 0, C_H + (ktl + 4) * 32, lane), b, y1a);
        y1b = mfma16(aread16(act, 1, C_H + (ktl + 4) * 32, lane), b, y1b);
      }
      st16(act, C_T0 + w * 16 + ln16, 0, rsub, y1a, bv1);
      st16(act, C_T0 + w * 16 + ln16, 1, rsub, y1b, bv1);
    }
    wg_barrier();

    // ===== s46: W2 (par0) — y2 -> C_T1 ; w>=8: issue ep + w8f/w9f =====
    writeS(st, ring, 0, tid, false);
    issueS(st, wsb + WB_W3, tid, false);
    wg_barrier();
    bf16x8 w8f[2], w9f[2];
    float ep[4];
    if (w < 8) {
      const bf16x8* rb = (const bf16x8*)(ring);
      f32x4 c0 = {}, c1 = {};
#pragma unroll
      for (int ktl = 0; ktl < 4; ++ktl) {
        bf16x8 b = rb[(ktl * 8 + w) * 64 + lane];
        c0 = mfma16(aread16(act, 0, C_T0 + ktl * 32, lane), b, c0);
        c1 = mfma16(aread16(act, 1, C_T0 + ktl * 32, lane), b, c1);
      }
      st16(act, C_T1 + w * 16 + ln16, 0, rsub, c0, bv2);
      st16(act, C_T1 + w * 16 + ln16, 1, rsub, c1, bv2);
    } else {
#pragma unroll
      for (int kt = 0; kt < 2; ++kt) {
        w8f[kt] = w8p[(size_t)(n2 * 2 + kt) * 64 + lane];
        w9f[kt] = w9p[(size_t)(n2 * 2 + kt) * 64 + lane];
      }
#pragma unroll
      for (int r = 0; r < 4; ++r)
        ep[r] = p.eps_prior[((size_t)j * BDIM + r0 + m2 * 16 + rsub + r) * ZDIM +
                            n2 * 16 + ln16];
    }
    wg_barrier();

    // ===== s47: W3 (par1) — y3 -> yW + outy =====
    writeS(st, ring, 1, tid, false);
    issueS(st, wsb + WB_W7SA, tid, false);
    wg_barrier();
    if (w < 8) {
      const bf16x8* rb = (const bf16x8*)(ring + 32768);
      f32x4 c0 = {}, c1 = {};
#pragma unroll
      for (int ktl = 0; ktl < 4; ++ktl) {
        bf16x8 b = rb[(ktl * 8 + w) * 64 + lane];
        c0 = mfma16(aread16(act, 0, C_T1 + ktl * 32, lane), b, c0);
        c1 = mfma16(aread16(act, 1, C_T1 + ktl * 32, lane), b, c1);
      }
#pragma unroll
      for (int r = 0; r < 4; ++r) {
        float yv0 = fmaxf(c0[r] + bv3, 0.f);
        float yv1 = fmaxf(c1[r] + bv3, 0.f);
        *(__bf16*)(act + act_off(rsub + r, yW + w * 16 + ln16)) = (__bf16)yv0;
        *(__bf16*)(act + act_off(16 + rsub + r, yW + w * 16 + ln16)) = (__bf16)yv1;
        __builtin_nontemporal_store(
            yv0, outy + ((size_t)(r0 + rsub + r) * STEPS + j) * FDIM + w * 16 + ln16);
        __builtin_nontemporal_store(
            yv1,
            outy + ((size_t)(r0 + 16 + rsub + r) * STEPS + j) * FDIM + w * 16 + ln16);
      }
    }
    wg_barrier();

    // ===== s48: W7SA (par0) — hzp c-part ; w<8: issue ei + w5f/w6f =====
    writeS(st, ring, 0, tid, false);
    issueS(st, wsb + WB_W7SB, tid, true);
    wg_barrier();
    f32x4 hza = {};
    bf16x8 w5f[2], w6f[2];
    float ei[4];
    if (w >= 8) {
      const bf16x8* rb = (const bf16x8*)(ring);
#pragma unroll
      for (int ktl = 0; ktl < 8; ++ktl)
        hza = mfma16(aread16(act, m2, C_C + ktl * 32, lane),
                     rb[(ktl * 4 + n2) * 64 + lane], hza);
    } else {
#pragma unroll
      for (int kt = 0; kt < 2; ++kt) {
        w5f[kt] = w5p[(size_t)(n2 * 2 + kt) * 64 + lane];
        w6f[kt] = w6p[(size_t)(n2 * 2 + kt) * 64 + lane];
      }
#pragma unroll
      for (int r = 0; r < 4; ++r)
        ei[r] = p.eps_inf[((size_t)j * BDIM + r0 + m2 * 16 + rsub + r) * ZDIM +
                          n2 * 16 + ln16];
    }
    wg_barrier();

    // ===== s49: W7SB (par1, 16KB) — hzp finish -> C_HZP =====
    writeS(st, ring, 1, tid, true);
    issueS(st, wsb + WB_W4C, tid, false);
    wg_barrier();
    if (w >= 8) {
      const bf16x8* rb = (const bf16x8*)(ring + 32768);
#pragma unroll
      for (int ktl = 0; ktl < 4; ++ktl)
        hza = mfma16(aread16(act, m2, yR + ktl * 32, lane),
                     rb[(ktl * 4 + n2) * 64 + lane], hza);
#pragma unroll
      for (int r = 0; r < 4; ++r)
        *(__bf16*)(act + act_off(m2 * 16 + rsub + r, C_HZP + n2 * 16 + ln16)) =
            (__bf16)fmaxf(hza[r] + b7f[r], 0.f);
    }
    wg_barrier();

    // ===== s50: W4C (par0) — hz c-part ; mean_p/lv_p + zp store =====
    writeS(st, ring, 0, tid, false);
    issueS(st, wsb + WB_W4YP, tid, false);
    wg_barrier();
    f32x4 vp = {};
    if (w >= 8) {
      const bf16x8* rb = (const bf16x8*)(ring);
#pragma unroll
      for (int ktl = 0; ktl < 8; ++ktl)
        vp = mfma16(aread16(act, m2, C_C + ktl * 32, lane),
                    rb[(ktl * 4 + n2) * 64 + lane], vp);
      f32x4 vm = {}, vl = {};
#pragma unroll
      for (int ktl = 0; ktl < 2; ++ktl) {
        bf16x8 a = aread16(act, m2, C_HZP + ktl * 32, lane);
        vm = mfma16(a, w8f[ktl], vm);
        vl = mfma16(a, w9f[ktl], vl);
      }
#pragma unroll
      for (int r = 0; r < 4; ++r) {
        float mp = fmaxf(vm[r] + bA, 0.f), lp = fmaxf(vl[r] + bB, 0.f);
        float zp = mp + ep[r] * __expf(0.5f * lp);
        __builtin_nontemporal_store(
            zp, outzp + ((size_t)(r0 + m2 * 16 + rsub + r) * STEPS + j) * ZDIM +
                    n2 * 16 + ln16);
      }
    }
    wg_barrier();

    // ===== s51: W4YP (par1) — hz finish -> C_HZ =====
    writeS(st, ring, 1, tid, false);
    issueS(st, wsb + WB_G, tid, false);  // next step slice 0 (wrap on last)
    wg_barrier();
    if (w >= 8) {
      const bf16x8* rb = (const bf16x8*)(ring + 32768);
#pragma unroll
      for (int ktl = 0; ktl < 8; ++ktl) {
        int col = (ktl < 4) ? (yW + ktl * 32) : (yR + (ktl - 4) * 32);
        vp = mfma16(aread16(act, m2, col, lane), rb[(ktl * 4 + n2) * 64 + lane], vp);
      }
#pragma unroll
      for (int r = 0; r < 4; ++r)
        *(__bf16*)(act + act_off(m2 * 16 + rsub + r, C_HZ + n2 * 16 + ln16)) =
            (__bf16)fmaxf(vp[r] + b4f[r], 0.f);
    }
    wg_barrier();

    // ===== epilogue: mean/lv + z (waves 0-7) -> outputs + C_Z =====
    if (w < 8) {
      f32x4 vm = {}, vl = {};
#pragma unroll
      for (int ktl = 0; ktl < 2; ++ktl) {
        bf16x8 a = aread16(act, m2, C_HZ + ktl * 32, lane);
        vm = mfma16(a, w5f[ktl], vm);
        vl = mfma16(a, w6f[ktl], vl);
      }
#pragma unroll
      for (int r = 0; r < 4; ++r) {
        int row = m2 * 16 + rsub + r, col = n2 * 16 + ln16;
        float m = fmaxf(vm[r] + bA, 0.f), l = fmaxf(vl[r] + bB, 0.f);
        float zn = m + ei[r] * __expf(0.5f * l);
        size_t ob = ((size_t)(r0 + row) * STEPS + j) * ZDIM + col;
        __builtin_nontemporal_store(m, outm + ob);
        __builtin_nontemporal_store(l, outl + ob);
        __builtin_nontemporal_store(zn, outz + ob);
        *(__bf16*)(act + act_off(row, C_Z + col)) = (__bf16)zn;
      }
    }
    // no extra barrier needed: next slice-0's post-write barrier orders C_Z
  }
}

extern "C" void kernel_launch(void* const* d_in, const int* in_sizes, int n_in,
                              void* d_out, int out_size, void* d_ws, size_t ws_size,
                              hipStream_t stream) {
  const float* h_i = (const float*)d_in[0];
  const float* input_t = (const float*)d_in[1];
  const float* eps_inf = (const float*)d_in[2];
  const float* eps_prior = (const float*)d_in[3];
  const float* Wx = (const float*)d_in[4];
  const float* Wh = (const float*)d_in[5];
  const float* b_lstm = (const float*)d_in[6];
  const float* w1 = (const float*)d_in[7];  const float* b1 = (const float*)d_in[8];
  const float* w2 = (const float*)d_in[9];  const float* b2 = (const float*)d_in[10];
  const float* w3 = (const float*)d_in[11]; const float* b3 = (const float*)d_in[12];
  const float* w4 = (const float*)d_in[13]; const float* b4 = (const float*)d_in[14];
  const float* w5 = (const float*)d_in[15]; const float* b5 = (const float*)d_in[16];
  const float* w6 = (const float*)d_in[17]; const float* b6 = (const float*)d_in[18];
  const float* w7 = (const float*)d_in[19]; const float* b7 = (const float*)d_in[20];
  const float* w8 = (const float*)d_in[21]; const float* b8 = (const float*)d_in[22];
  const float* w9 = (const float*)d_in[23]; const float* b9 = (const float*)d_in[24];
  const float* alpha = (const float*)d_in[25];
  const float* beta = (const float*)d_in[26];
  const float* mu0 = (const float*)d_in[27];
  __bf16* ws = (__bf16*)d_ws;

  pack_gates<<<(44 * 32 * 64 + 255) / 256, 256, 0, stream>>>(Wx, Wh, ws);
  auto T = [&](const float* src, int row0, int K, int N, unsigned elem_off) {
    int total = (K / 32) * (N / 16) * 64;
    pack_tail<<<(total + 255) / 256, 256, 0, stream>>>(src, row0, K, N, ws + elem_off);
  };
  T(w1, 0, 256, 128, 720896u);    // W1A/W1B
  T(w2, 0, 128, 128, 753664u);    // W2
  T(w3, 0, 128, 128, 770048u);    // W3
  T(w7, 256, 384, 64, 786432u);   // W7SA/W7SB [c|yp]
  T(w4, 256, 512, 64, 811008u);   // W4C/W4YP [c|y|yp]
  auto S = [&](const float* src, int row0, int K, int N, unsigned elem_off) {
    PSeg s; s.p = src; s.row0 = row0; s.len = K;
    int total = (K / 32) * (N / 16) * 64;
    pack_w<<<(total + 255) / 256, 256, 0, stream>>>(s, K, N, ws + elem_off);
  };
  S(w4, 0, 256, 64, PW_W4H);
  S(w7, 0, 256, 64, PW_W7H);
  S(w5, 0, 64, 64, PW_W5);
  S(w6, 0, 64, 64, PW_W6);
  S(w8, 0, 64, 64, PW_W8);
  S(w9, 0, 64, 64, PW_W9);

  Params p;
  p.h_i = h_i; p.input_t = input_t; p.eps_inf = eps_inf; p.eps_prior = eps_prior;
  p.b_lstm = b_lstm; p.b1 = b1; p.b2 = b2; p.b3 = b3; p.b4 = b4; p.b5 = b5;
  p.b6 = b6; p.b7 = b7; p.b8 = b8; p.b9 = b9;
  p.alpha = alpha; p.beta = beta; p.mu0 = mu0;
  p.wpack = ws;
  p.out = (float*)d_out;

  decoder_main<<<256, 1024, 0, stream>>>(p);
}

// Round 11
// 5579.499 us; speedup vs baseline: 1.0741x; 1.0741x over previous
//
#include <hip/hip_runtime.h>

// ---------------------------------------------------------------------------
// Fused decoder R11: B=8192 x 40 steps, 1 WG (512 thr, 8 waves) per 32 rows,
// grid=256, waves_per_eu(2,2) -> 128 VGPR (R7-proven). Weights stream
// global->regs->LDS through a 2x32KB ring (52 slices/step: 44 gates
// @32x32x16 + 8 tail @16x16x32). R10's schedule/layouts (proven correct);
// R11 removes the 64-VGPR spill storm by using the 512-thread/128-reg build.
// ---------------------------------------------------------------------------

#define BDIM  8192
#define HDIM  256
#define FDIM  128
#define ZDIM  64
#define TDIM  43
#define STEPS 40

typedef __attribute__((ext_vector_type(8)))  __bf16 bf16x8;
typedef __attribute__((ext_vector_type(4)))  float  f32x4;
typedef __attribute__((ext_vector_type(16))) float  f32x16;

// act: 32 rows x 1344 bf16 cols, stride 2704B (676 dw == 4 mod 32), +16B/8rows
#define ACT_STRIDE 2704
#define C_Z   0      // z (64)
#define C_HI  64     // h_i (256, permanent)
#define C_Y0  320    // y parity 0 (128)
#define C_Y1  448    // y parity 1 (128)
#define C_H   576    // h single buffer (256)
#define C_C   832    // c_new (256)
#define C_T0  1088   // y1 (128) — overlaid by hzp
#define C_T1  1216   // y2 (128) — overlaid by hz
#define C_HZP C_T0
#define C_HZ  C_T1

// ws BYTE offsets (streamed slices) / ELEM offsets (register-loaded smalls)
#define WB_G    0u         // 44 slices x 32KB (gates K=704: z|h_i|yp|h)
#define WB_W1A  1441792u
#define WB_W1B  1474560u
#define WB_W2   1507328u
#define WB_W3   1540096u
#define WB_W7SA 1572864u   // W7S kt0-7 (c-part, 32KB)
#define WB_W7SB 1605632u   // W7S kt8-11 (yp-part, 16KB)
#define WB_W4C  1622016u   // W4S kt0-7 (c-part, 32KB)
#define WB_W4YP 1654784u   // W4S kt8-15 (y|yp, 32KB)
#define PW_W4H  843776u
#define PW_W7H  860160u
#define PW_W5   876544u
#define PW_W6   880640u
#define PW_W8   884736u
#define PW_W9   888832u

__device__ __forceinline__ int act_off(int row, int col) {
  return row * ACT_STRIDE + ((row >> 3) << 4) + (col << 1);
}
__device__ __forceinline__ f32x16 mfma32(bf16x8 a, bf16x8 b, f32x16 c) {
  return __builtin_amdgcn_mfma_f32_32x32x16_bf16(a, b, c, 0, 0, 0);
}
__device__ __forceinline__ f32x4 mfma16(bf16x8 a, bf16x8 b, f32x4 c) {
  return __builtin_amdgcn_mfma_f32_16x16x32_bf16(a, b, c, 0, 0, 0);
}
__device__ __forceinline__ float sigm(float x) { return 1.f / (1.f + __expf(-x)); }
__device__ __forceinline__ float tanh_f(float x) {
  float t = __expf(-2.f * fabsf(x));
  float r = (1.f - t) / (1.f + t);
  return x < 0.f ? -r : r;
}
// lgkmcnt-only barrier: staging global loads stay in flight across it.
__device__ __forceinline__ void wg_barrier() {
  asm volatile("s_waitcnt lgkmcnt(0)" ::: "memory");
  __builtin_amdgcn_s_barrier();
  __builtin_amdgcn_sched_barrier(0);
}
// reg-staged slice: 512 threads x 64B (full) or 32B (half)
struct StageReg { uint4 a, b, c, d; };
__device__ __forceinline__ void issueS(StageReg& st, const unsigned char* src, int tid,
                                       bool half) {
  st.a = *(const uint4*)(src + tid * 16);
  st.b = *(const uint4*)(src + 8192 + tid * 16);
  if (!half) {
    st.c = *(const uint4*)(src + 16384 + tid * 16);
    st.d = *(const uint4*)(src + 24576 + tid * 16);
  }
}
__device__ __forceinline__ void writeS(const StageReg& st, unsigned char* ring, int par,
                                       int tid, bool half) {
  *(uint4*)(ring + par * 32768 + tid * 16) = st.a;
  *(uint4*)(ring + par * 32768 + 8192 + tid * 16) = st.b;
  if (!half) {
    *(uint4*)(ring + par * 32768 + 16384 + tid * 16) = st.c;
    *(uint4*)(ring + par * 32768 + 24576 + tid * 16) = st.d;
  }
}
__device__ __forceinline__ bf16x8 aread16(const unsigned char* a, int mt, int col,
                                          int lane) {
  return *(const bf16x8*)(a + act_off(mt * 16 + (lane & 15), col + ((lane >> 4) << 3)));
}
__device__ __forceinline__ bf16x8 aread32(const unsigned char* a, int col, int lane) {
  return *(const bf16x8*)(a + act_off(lane & 31, col + ((lane >> 5) << 3)));
}
__device__ __forceinline__ void st16(unsigned char* a, int col, int mt, int rsub,
                                     f32x4 v, float bv) {
#pragma unroll
  for (int r = 0; r < 4; ++r)
    *(__bf16*)(a + act_off(mt * 16 + rsub + r, col)) = (__bf16)fmaxf(v[r] + bv, 0.f);
}

// ---------------------------------------------------------------------------
// Packers (layouts proven in R10)
// ---------------------------------------------------------------------------
__global__ __launch_bounds__(256) void pack_gates(const float* __restrict__ Wx,
                                                  const float* __restrict__ Wh,
                                                  __bf16* __restrict__ dst) {
  int f = blockIdx.x * 256 + threadIdx.x;
  if (f >= 44 * 32 * 64) return;
  int lane = f & 63, t = f >> 6, ct = t & 31, s = t >> 5;
  int k0 = s * 16 + ((lane >> 5) << 3);
  int col = (ct << 5) + (lane & 31);
  bf16x8 v;
#pragma unroll
  for (int j = 0; j < 8; ++j) {
    int k = k0 + j;
    v[j] = (__bf16)((k < 448) ? Wx[(size_t)k * 1024 + col]
                              : Wh[(size_t)(k - 448) * 1024 + col]);
  }
  *(bf16x8*)(dst + (size_t)f * 8) = v;
}
__global__ __launch_bounds__(256) void pack_tail(const float* __restrict__ src, int row0,
                                                 int K, int N, __bf16* __restrict__ dst) {
  int NT = N >> 4, KT = K >> 5;
  int f = blockIdx.x * 256 + threadIdx.x;
  if (f >= KT * NT * 64) return;
  int lane = f & 63, t = f >> 6, nt = t % NT, kt = t / NT;
  int k0 = row0 + kt * 32 + ((lane >> 4) << 3);
  int col = (nt << 4) + (lane & 15);
  bf16x8 v;
#pragma unroll
  for (int j = 0; j < 8; ++j) v[j] = (__bf16)src[(size_t)(k0 + j) * N + col];
  *(bf16x8*)(dst + (size_t)f * 8) = v;
}
struct PSeg { const float* p; int row0; int len; };
__global__ __launch_bounds__(256) void pack_w(PSeg s0, int K, int N,
                                              __bf16* __restrict__ dst) {
  int KT = K >> 5;
  int total = KT * (N >> 4) * 64;
  int f = blockIdx.x * 256 + threadIdx.x;
  if (f >= total) return;
  int lane = f & 63, tile = f >> 6, kt = tile % KT, nt = tile / KT;
  int k0 = kt * 32 + ((lane >> 4) << 3);
  int n = (nt << 4) + (lane & 15);
  bf16x8 v;
#pragma unroll
  for (int j = 0; j < 8; ++j)
    v[j] = (__bf16)s0.p[(size_t)(s0.row0 + k0 + j) * N + n];
  *(bf16x8*)(dst + (size_t)f * 8) = v;
}

struct Params {
  const float *h_i, *input_t, *eps_inf, *eps_prior;
  const float *b_lstm, *b1, *b2, *b3, *b4, *b5, *b6, *b7, *b8, *b9;
  const float *alpha, *beta, *mu0;
  const __bf16* wpack;
  float* out;
};

__global__ __launch_bounds__(512) __attribute__((amdgpu_waves_per_eu(2, 2)))
void decoder_main(Params p) {
  __shared__ __align__(16) unsigned char act[86592];
  __shared__ __align__(16) unsigned char ring[65536];
  __shared__ float inten[STEPS * 32];

  const int tid = threadIdx.x;
  const int w = tid >> 6;            // 0..7
  const int lane = tid & 63;
  const int ln16 = lane & 15;
  const int nl = lane & 31;
  const int rsub = (lane >> 4) << 2;
  const int r0 = blockIdx.x * 32;
  const unsigned char* wsb = (const unsigned char*)p.wpack;

  for (int i = tid; i < 86592 / 4; i += 512) ((unsigned int*)act)[i] = 0u;
  __syncthreads();
  for (int i = tid; i < 32 * 256; i += 512) {
    int row = i >> 8, col = i & 255;
    *(__bf16*)(act + act_off(row, C_HI + col)) =
        (__bf16)p.h_i[(size_t)(r0 + row) * HDIM + col];
  }
  {
    float ab = p.alpha[0] * p.beta[0], mu = p.mu0[0];
    for (int t = tid; t < 32 * STEPS; t += 512) {
      int row = t & 31, j = t >> 5;
      const float* tp = p.input_t + (size_t)(r0 + row) * TDIM;
      float tc = tp[j + 3];
      float s = 0.f;
      for (int idx = 0; idx < j + 3; ++idx) s += __expf(tp[idx] - tc);
      inten[j * 32 + row] = mu + ab * s;
    }
  }
  __syncthreads();

  const __bf16* W = p.wpack;
  const bf16x8* w4h = (const bf16x8*)(W + PW_W4H);
  const bf16x8* w7h = (const bf16x8*)(W + PW_W7H);
  const bf16x8* w5p = (const bf16x8*)(W + PW_W5);
  const bf16x8* w6p = (const bf16x8*)(W + PW_W6);
  const bf16x8* w8p = (const bf16x8*)(W + PW_W8);
  const bf16x8* w9p = (const bf16x8*)(W + PW_W9);

  const int n2 = w & 3, m2 = w >> 2;
  // startup folds: every wave computes h_i@w4h+b4, h_i@w7h+b7 at (n2,m2)
  f32x4 b4f = {}, b7f = {};
  {
    f32x4 v4 = {}, v7 = {};
#pragma unroll
    for (int kt = 0; kt < 8; ++kt) {
      bf16x8 a = aread16(act, m2, C_HI + kt * 32, lane);
      v4 = mfma16(a, w4h[(size_t)(n2 * 8 + kt) * 64 + lane], v4);
      v7 = mfma16(a, w7h[(size_t)(n2 * 8 + kt) * 64 + lane], v7);
    }
    float b4v = p.b4[n2 * 16 + ln16], b7v = p.b7[n2 * 16 + ln16];
#pragma unroll
    for (int r = 0; r < 4; ++r) { b4f[r] = v4[r] + b4v; b7f[r] = v7[r] + b7v; }
  }
  // bias hoists (every wave needs all of them now)
  const float bi = p.b_lstm[w * 32 + nl];
  const float bf2 = p.b_lstm[256 + w * 32 + nl];
  const float bg = p.b_lstm[512 + w * 32 + nl];
  const float bo = p.b_lstm[768 + w * 32 + nl];
  const float bv1 = p.b1[w * 16 + ln16];
  const float bv2 = p.b2[w * 16 + ln16];
  const float bv3 = p.b3[w * 16 + ln16];
  const float b5v = p.b5[n2 * 16 + ln16];
  const float b6v = p.b6[n2 * 16 + ln16];
  const float b8v = p.b8[n2 * 16 + ln16];
  const float b9v = p.b9[n2 * 16 + ln16];
  f32x16 c_st = {};
  __syncthreads();

  float* outy = p.out;
  float* outm = p.out + (size_t)BDIM * STEPS * FDIM;
  float* outl = outm + (size_t)BDIM * STEPS * ZDIM;
  float* outz = outl + (size_t)BDIM * STEPS * ZDIM;
  float* outzp = outz + (size_t)BDIM * STEPS * ZDIM;

  StageReg st;
  issueS(st, wsb + WB_G, tid, false);  // slice 0 of step 0

  for (int j = 0; j < STEPS; ++j) {
    const int yW = (j & 1) ? C_Y1 : C_Y0, yR = (j & 1) ? C_Y0 : C_Y1;

    // ===== gates: 44 slices (par = k&1), all 8 waves consume =====
    f32x16 a0 = {}, a1 = {}, a2 = {}, a3 = {};
    for (int k = 0; k < 44; ++k) {
      writeS(st, ring, k & 1, tid, false);
      const unsigned char* nxt =
          (k < 43) ? (wsb + WB_G + (unsigned)(k + 1) * 32768u) : (wsb + WB_W1A);
      issueS(st, nxt, tid, false);
      wg_barrier();
      {
        const bf16x8* rb = (const bf16x8*)(ring + (k & 1) * 32768);
        int colb = (k < 4) ? (C_Z + k * 16)
                           : (k < 20) ? (C_HI + (k - 4) * 16)
                                      : (k < 28) ? (yR + (k - 20) * 16)
                                                 : (C_H + (k - 28) * 16);
        bf16x8 a = aread32(act, colb, lane);
        a0 = mfma32(a, rb[(0 * 8 + w) * 64 + lane], a0);
        a1 = mfma32(a, rb[(1 * 8 + w) * 64 + lane], a1);
        a2 = mfma32(a, rb[(2 * 8 + w) * 64 + lane], a2);
        a3 = mfma32(a, rb[(3 * 8 + w) * 64 + lane], a3);
      }
      wg_barrier();
    }

    // ===== LSTM pointwise -> C_C, C_H =====
    {
#pragma unroll
      for (int r = 0; r < 16; ++r) {
        int row = (r & 3) + ((r >> 2) << 3) + ((lane >> 5) << 2);
        float ig = sigm(a0[r] + bi);
        float fg = sigm(a1[r] + bf2);
        float gg = tanh_f(a2[r] + bg);
        float og = sigm(a3[r] + bo);
        float cn = fg * c_st[r] + ig * gg;
        float hn = og * tanh_f(cn);
        c_st[r] = inten[j * 32 + row] * cn;
        *(__bf16*)(act + act_off(row, C_C + w * 32 + nl)) = (__bf16)cn;
        *(__bf16*)(act + act_off(row, C_H + w * 32 + nl)) = (__bf16)hn;
      }
    }

    // ===== s44: W1A (par0) — y1 part1 =====
    writeS(st, ring, 0, tid, false);
    issueS(st, wsb + WB_W1B, tid, false);
    wg_barrier();
    f32x4 y1a = {}, y1b = {};
    {
      const bf16x8* rb = (const bf16x8*)(ring);
#pragma unroll
      for (int ktl = 0; ktl < 4; ++ktl) {
        bf16x8 b = rb[(ktl * 8 + w) * 64 + lane];
        y1a = mfma16(aread16(act, 0, C_H + ktl * 32, lane), b, y1a);
        y1b = mfma16(aread16(act, 1, C_H + ktl * 32, lane), b, y1b);
      }
    }
    wg_barrier();

    // ===== s45: W1B (par1) — y1 finish -> C_T0 =====
    writeS(st, ring, 1, tid, false);
    issueS(st, wsb + WB_W2, tid, false);
    wg_barrier();
    {
      const bf16x8* rb = (const bf16x8*)(ring + 32768);
#pragma unroll
      for (int ktl = 0; ktl < 4; ++ktl) {
        bf16x8 b = rb[(ktl * 8 + w) * 64 + lane];
        y1a = mfma16(aread16(act, 0, C_H + (ktl + 4) * 32, lane), b, y1a);
        y1b = mfma16(aread16(act, 1, C_H + (ktl + 4) * 32, lane), b, y1b);
      }
      st16(act, C_T0 + w * 16 + ln16, 0, rsub, y1a, bv1);
      st16(act, C_T0 + w * 16 + ln16, 1, rsub, y1b, bv1);
    }
    wg_barrier();

    // ===== s46: W2 (par0) — y2 -> C_T1 ; also issue ep + w8f/w9f =====
    writeS(st, ring, 0, tid, false);
    issueS(st, wsb + WB_W3, tid, false);
    wg_barrier();
    bf16x8 w8f[2], w9f[2];
    float ep[4];
    {
      const bf16x8* rb = (const bf16x8*)(ring);
      f32x4 c0 = {}, c1 = {};
#pragma unroll
      for (int ktl = 0; ktl < 4; ++ktl) {
        bf16x8 b = rb[(ktl * 8 + w) * 64 + lane];
        c0 = mfma16(aread16(act, 0, C_T0 + ktl * 32, lane), b, c0);
        c1 = mfma16(aread16(act, 1, C_T0 + ktl * 32, lane), b, c1);
      }
      st16(act, C_T1 + w * 16 + ln16, 0, rsub, c0, bv2);
      st16(act, C_T1 + w * 16 + ln16, 1, rsub, c1, bv2);
#pragma unroll
      for (int kt = 0; kt < 2; ++kt) {
        w8f[kt] = w8p[(size_t)(n2 * 2 + kt) * 64 + lane];
        w9f[kt] = w9p[(size_t)(n2 * 2 + kt) * 64 + lane];
      }
#pragma unroll
      for (int r = 0; r < 4; ++r)
        ep[r] = p.eps_prior[((size_t)j * BDIM + r0 + m2 * 16 + rsub + r) * ZDIM +
                            n2 * 16 + ln16];
    }
    wg_barrier();

    // ===== s47: W3 (par1) — y3 -> yW + outy =====
    writeS(st, ring, 1, tid, false);
    issueS(st, wsb + WB_W7SA, tid, false);
    wg_barrier();
    {
      const bf16x8* rb = (const bf16x8*)(ring + 32768);
      f32x4 c0 = {}, c1 = {};
#pragma unroll
      for (int ktl = 0; ktl < 4; ++ktl) {
        bf16x8 b = rb[(ktl * 8 + w) * 64 + lane];
        c0 = mfma16(aread16(act, 0, C_T1 + ktl * 32, lane), b, c0);
        c1 = mfma16(aread16(act, 1, C_T1 + ktl * 32, lane), b, c1);
      }
#pragma unroll
      for (int r = 0; r < 4; ++r) {
        float yv0 = fmaxf(c0[r] + bv3, 0.f);
        float yv1 = fmaxf(c1[r] + bv3, 0.f);
        *(__bf16*)(act + act_off(rsub + r, yW + w * 16 + ln16)) = (__bf16)yv0;
        *(__bf16*)(act + act_off(16 + rsub + r, yW + w * 16 + ln16)) = (__bf16)yv1;
        __builtin_nontemporal_store(
            yv0, outy + ((size_t)(r0 + rsub + r) * STEPS + j) * FDIM + w * 16 + ln16);
        __builtin_nontemporal_store(
            yv1,
            outy + ((size_t)(r0 + 16 + rsub + r) * STEPS + j) * FDIM + w * 16 + ln16);
      }
    }
    wg_barrier();

    // ===== s48: W7SA (par0) — hzp c-part ; also issue ei + w5f/w6f =====
    writeS(st, ring, 0, tid, false);
    issueS(st, wsb + WB_W7SB, tid, true);
    wg_barrier();
    f32x4 hza = {};
    bf16x8 w5f[2], w6f[2];
    float ei[4];
    {
      const bf16x8* rb = (const bf16x8*)(ring);
#pragma unroll
      for (int ktl = 0; ktl < 8; ++ktl)
        hza = mfma16(aread16(act, m2, C_C + ktl * 32, lane),
                     rb[(ktl * 4 + n2) * 64 + lane], hza);
#pragma unroll
      for (int kt = 0; kt < 2; ++kt) {
        w5f[kt] = w5p[(size_t)(n2 * 2 + kt) * 64 + lane];
        w6f[kt] = w6p[(size_t)(n2 * 2 + kt) * 64 + lane];
      }
#pragma unroll
      for (int r = 0; r < 4; ++r)
        ei[r] = p.eps_inf[((size_t)j * BDIM + r0 + m2 * 16 + rsub + r) * ZDIM +
                          n2 * 16 + ln16];
    }
    wg_barrier();

    // ===== s49: W7SB (par1, 16KB) — hzp finish -> C_HZP =====
    writeS(st, ring, 1, tid, true);
    issueS(st, wsb + WB_W4C, tid, false);
    wg_barrier();
    {
      const bf16x8* rb = (const bf16x8*)(ring + 32768);
#pragma unroll
      for (int ktl = 0; ktl < 4; ++ktl)
        hza = mfma16(aread16(act, m2, yR + ktl * 32, lane),
                     rb[(ktl * 4 + n2) * 64 + lane], hza);
#pragma unroll
      for (int r = 0; r < 4; ++r)
        *(__bf16*)(act + act_off(m2 * 16 + rsub + r, C_HZP + n2 * 16 + ln16)) =
            (__bf16)fmaxf(hza[r] + b7f[r], 0.f);
    }
    wg_barrier();

    // ===== s50: W4C (par0) — hz c-part ; prior sampling + zp store =====
    writeS(st, ring, 0, tid, false);
    issueS(st, wsb + WB_W4YP, tid, false);
    wg_barrier();
    f32x4 vp = {};
    {
      const bf16x8* rb = (const bf16x8*)(ring);
#pragma unroll
      for (int ktl = 0; ktl < 8; ++ktl)
        vp = mfma16(aread16(act, m2, C_C + ktl * 32, lane),
                    rb[(ktl * 4 + n2) * 64 + lane], vp);
      f32x4 vm = {}, vl = {};
#pragma unroll
      for (int ktl = 0; ktl < 2; ++ktl) {
        bf16x8 a = aread16(act, m2, C_HZP + ktl * 32, lane);
        vm = mfma16(a, w8f[ktl], vm);
        vl = mfma16(a, w9f[ktl], vl);
      }
#pragma unroll
      for (int r = 0; r < 4; ++r) {
        float mp = fmaxf(vm[r] + b8v, 0.f), lp = fmaxf(vl[r] + b9v, 0.f);
        float zp = mp + ep[r] * __expf(0.5f * lp);
        __builtin_nontemporal_store(
            zp, outzp + ((size_t)(r0 + m2 * 16 + rsub + r) * STEPS + j) * ZDIM +
                    n2 * 16 + ln16);
      }
    }
    wg_barrier();

    // ===== s51: W4YP (par1) — hz finish -> C_HZ =====
    writeS(st, ring, 1, tid, false);
    issueS(st, wsb + WB_G, tid, false);  // next step slice 0 (wrap on last)
    wg_barrier();
    {
      const bf16x8* rb = (const bf16x8*)(ring + 32768);
#pragma unroll
      for (int ktl = 0; ktl < 8; ++ktl) {
        int col = (ktl < 4) ? (yW + ktl * 32) : (yR + (ktl - 4) * 32);
        vp = mfma16(aread16(act, m2, col, lane), rb[(ktl * 4 + n2) * 64 + lane], vp);
      }
#pragma unroll
      for (int r = 0; r < 4; ++r)
        *(__bf16*)(act + act_off(m2 * 16 + rsub + r, C_HZ + n2 * 16 + ln16)) =
            (__bf16)fmaxf(vp[r] + b4f[r], 0.f);
    }
    wg_barrier();

    // ===== epilogue: mean/lv + z -> outputs + C_Z =====
    {
      f32x4 vm = {}, vl = {};
#pragma unroll
      for (int ktl = 0; ktl < 2; ++ktl) {
        bf16x8 a = aread16(act, m2, C_HZ + ktl * 32, lane);
        vm = mfma16(a, w5f[ktl], vm);
        vl = mfma16(a, w6f[ktl], vl);
      }
#pragma unroll
      for (int r = 0; r < 4; ++r) {
        int row = m2 * 16 + rsub + r, col = n2 * 16 + ln16;
        float m = fmaxf(vm[r] + b5v, 0.f), l = fmaxf(vl[r] + b6v, 0.f);
        float zn = m + ei[r] * __expf(0.5f * l);
        size_t ob = ((size_t)(r0 + row) * STEPS + j) * ZDIM + col;
        __builtin_nontemporal_store(m, outm + ob);
        __builtin_nontemporal_store(l, outl + ob);
        __builtin_nontemporal_store(zn, outz + ob);
        *(__bf16*)(act + act_off(row, C_Z + col)) = (__bf16)zn;
      }
    }
    // next gates k=0's post-write barrier orders C_Z for its readers
  }
}

extern "C" void kernel_launch(void* const* d_in, const int* in_sizes, int n_in,
                              void* d_out, int out_size, void* d_ws, size_t ws_size,
                              hipStream_t stream) {
  const float* h_i = (const float*)d_in[0];
  const float* input_t = (const float*)d_in[1];
  const float* eps_inf = (const float*)d_in[2];
  const float* eps_prior = (const float*)d_in[3];
  const float* Wx = (const float*)d_in[4];
  const float* Wh = (const float*)d_in[5];
  const float* b_lstm = (const float*)d_in[6];
  const float* w1 = (const float*)d_in[7];  const float* b1 = (const float*)d_in[8];
  const float* w2 = (const float*)d_in[9];  const float* b2 = (const float*)d_in[10];
  const float* w3 = (const float*)d_in[11]; const float* b3 = (const float*)d_in[12];
  const float* w4 = (const float*)d_in[13]; const float* b4 = (const float*)d_in[14];
  const float* w5 = (const float*)d_in[15]; const float* b5 = (const float*)d_in[16];
  const float* w6 = (const float*)d_in[17]; const float* b6 = (const float*)d_in[18];
  const float* w7 = (const float*)d_in[19]; const float* b7 = (const float*)d_in[20];
  const float* w8 = (const float*)d_in[21]; const float* b8 = (const float*)d_in[22];
  const float* w9 = (const float*)d_in[23]; const float* b9 = (const float*)d_in[24];
  const float* alpha = (const float*)d_in[25];
  const float* beta = (const float*)d_in[26];
  const float* mu0 = (const float*)d_in[27];
  __bf16* ws = (__bf16*)d_ws;

  pack_gates<<<(44 * 32 * 64 + 255) / 256, 256, 0, stream>>>(Wx, Wh, ws);
  auto T = [&](const float* src, int row0, int K, int N, unsigned elem_off) {
    int total = (K / 32) * (N / 16) * 64;
    pack_tail<<<(total + 255) / 256, 256, 0, stream>>>(src, row0, K, N, ws + elem_off);
  };
  T(w1, 0, 256, 128, 720896u);    // W1A/W1B
  T(w2, 0, 128, 128, 753664u);    // W2
  T(w3, 0, 128, 128, 770048u);    // W3
  T(w7, 256, 384, 64, 786432u);   // W7SA/W7SB [c|yp]
  T(w4, 256, 512, 64, 811008u);   // W4C/W4YP [c|y|yp]
  auto S = [&](const float* src, int row0, int K, int N, unsigned elem_off) {
    PSeg s; s.p = src; s.row0 = row0; s.len = K;
    int total = (K / 32) * (N / 16) * 64;
    pack_w<<<(total + 255) / 256, 256, 0, stream>>>(s, K, N, ws + elem_off);
  };
  S(w4, 0, 256, 64, PW_W4H);
  S(w7, 0, 256, 64, PW_W7H);
  S(w5, 0, 64, 64, PW_W5);
  S(w6, 0, 64, 64, PW_W6);
  S(w8, 0, 64, 64, PW_W8);
  S(w9, 0, 64, 64, PW_W9);

  Params p;
  p.h_i = h_i; p.input_t = input_t; p.eps_inf = eps_inf; p.eps_prior = eps_prior;
  p.b_lstm = b_lstm; p.b1 = b1; p.b2 = b2; p.b3 = b3; p.b4 = b4; p.b5 = b5;
  p.b6 = b6; p.b7 = b7; p.b8 = b8; p.b9 = b9;
  p.alpha = alpha; p.beta = beta; p.mu0 = mu0;
  p.wpack = ws;
  p.out = (float*)d_out;

  decoder_main<<<256, 512, 0, stream>>>(p);
}

// Round 12
// 4537.575 us; speedup vs baseline: 1.3207x; 1.2296x over previous
//
#include <hip/hip_runtime.h>

// ---------------------------------------------------------------------------
// Fused decoder R12: B=8192 x 40 steps. 16 rows/WG, 512 threads (8 waves),
// grid=512 -> 2 WGs/CU (4 waves/SIMD, 128 VGPR — R7/R11-proven build).
// R4's proven 6-phase schedule and weight layouts, M=16 (acc 32 VGPR).
// Gates weights: rotating X/Y 4-frag asm-pinned chunks, counted vmcnt(4);
// other phases batch-issue asm loads + vmcnt(0). h_i folds + small weights
// persist in registers. Next-step gates chunks issued in phase F.
// ---------------------------------------------------------------------------

#define BDIM  8192
#define HDIM  256
#define FDIM  128
#define ZDIM  64
#define TDIM  43
#define STEPS 40
#define ROWS  16

typedef __attribute__((ext_vector_type(8))) __bf16 bf16x8;
typedef __attribute__((ext_vector_type(4))) float  f32x4;
typedef __attribute__((ext_vector_type(4))) int    i32x4;

// LDS activation buffer (cols are bf16 elements) — R4 column map, 16 rows
#define ACT_STRIDE 3248
#define C_Z   0      // z (64)
#define C_Y0  64     // y parity 0 (128)
#define C_Y1  192    // y parity 1 (128)
#define C_H0  320    // h parity 0 (256)
#define C_H1  576    // h parity 1 (256)
#define C_C   832    // c_new (256) (h_i during startup folds)
#define C_T0  1088   // y1 (128)
#define C_T1  1216   // y2 (128)
#define C_HZ  1344   // hz (64)
#define C_HZP 1408   // hzp (64)

// packed-weight offsets in __bf16 elements (R4 layout, proven)
#define PW_GS  0u         // gates [z|yp|h] K=448 N=1024 (KT=14)
#define PW_GHI 458752u    // gates h_i part K=256 N=1024 (KT=8)
#define PW_W1  720896u    // K=256 N=128 (KT=8)
#define PW_W2  753664u    // K=128 N=128 (KT=4)
#define PW_W3  770048u    // K=128 N=128 (KT=4)
#define PW_W4S 786432u    // w4 rows 256:768 [c|y|yp] K=512 N=64 (KT=16)
#define PW_W4H 819200u    // w4 rows 0:256 K=256 N=64 (KT=8)
#define PW_W5  835584u    // K=64 N=64 (KT=2)
#define PW_W6  839680u
#define PW_W7S 843776u    // w7 rows 256:640 [c|yp] K=384 N=64 (KT=12)
#define PW_W7H 868352u    // w7 rows 0:256 K=256 N=64 (KT=8)
#define PW_W8  884736u
#define PW_W9  888832u

#define SB() __builtin_amdgcn_sched_barrier(0)
#define VMW(N)                                             \
  do {                                                     \
    asm volatile("s_waitcnt vmcnt(" #N ")" ::: "memory");  \
    SB();                                                  \
  } while (0)

__device__ __forceinline__ int act_off(int row, int col) {
  return row * ACT_STRIDE + ((row >> 3) << 4) + (col << 1);
}
__device__ __forceinline__ f32x4 mfma16(bf16x8 a, bf16x8 b, f32x4 c) {
  return __builtin_amdgcn_mfma_f32_16x16x32_bf16(a, b, c, 0, 0, 0);
}
__device__ __forceinline__ float sigm(float x) { return 1.f / (1.f + __expf(-x)); }
__device__ __forceinline__ float tanh_f(float x) {
  float t = __expf(-2.f * fabsf(x));
  float r = (1.f - t) / (1.f + t);
  return x < 0.f ? -r : r;
}
__device__ __forceinline__ void wg_barrier() {
  asm volatile("s_waitcnt lgkmcnt(0)" ::: "memory");
  __builtin_amdgcn_s_barrier();
  __builtin_amdgcn_sched_barrier(0);
}
// asm-pinned load: forced distinct in-flight dest regs (R7-proven mechanism)
__device__ __forceinline__ bf16x8 gld(const bf16x8* p) {
  i32x4 r;
  asm volatile("global_load_dwordx4 %0, %1, off" : "=v"(r) : "v"(p));
  return __builtin_bit_cast(bf16x8, r);
}
// A-fragment read: lane l holds A[l&15][k=(l>>4)*8+j]  (M=16, single mtile)
__device__ __forceinline__ bf16x8 aread(const unsigned char* a, int col, int lane) {
  return *(const bf16x8*)(a + act_off(lane & 15, col + ((lane >> 4) << 3)));
}
__device__ __forceinline__ void st16(unsigned char* a, int col, int rsub, f32x4 v,
                                     float bv) {
#pragma unroll
  for (int r = 0; r < 4; ++r)
    *(__bf16*)(a + act_off(rsub + r, col)) = (__bf16)fmaxf(v[r] + bv, 0.f);
}
__device__ __forceinline__ unsigned int pk2(float a, float b) {
  union { __bf16 h; unsigned short u; } x, y;
  x.h = (__bf16)a; y.h = (__bf16)b;
  return (unsigned int)x.u | ((unsigned int)y.u << 16);
}
__device__ __forceinline__ float upkf(unsigned int u, int hi) {
  union { unsigned int i; float f; } c;
  c.i = hi ? (u & 0xffff0000u) : (u << 16);
  return c.f;
}

// ---------------------------------------------------------------------------
// Packer (R4's, proven): up to 3 K-stacked segments -> 16-wide B-fragments
// frag f=(nt*KT+kt)*64+lane holds W[kt*32+(lane>>4)*8+j][nt*16+(lane&15)]
// ---------------------------------------------------------------------------
struct PSeg { const float* p; int row0; int len; };

__global__ __launch_bounds__(256) void pack_w(PSeg s0, PSeg s1, PSeg s2,
                                              int K, int N, __bf16* __restrict__ dst) {
  int f = blockIdx.x * 256 + threadIdx.x;
  int KT = K >> 5;
  int total = KT * (N >> 4) * 64;
  if (f >= total) return;
  int lane = f & 63;
  int tile = f >> 6;
  int kt = tile % KT;
  int nt = tile / KT;
  int k0 = kt * 32 + ((lane >> 4) << 3);
  int n = (nt << 4) + (lane & 15);
  bf16x8 v;
#pragma unroll
  for (int j = 0; j < 8; ++j) {
    int k = k0 + j;
    const float* src;
    int r;
    if (k < s0.len) { src = s0.p; r = s0.row0 + k; }
    else if (k < s0.len + s1.len) { src = s1.p; r = s1.row0 + (k - s0.len); }
    else { src = s2.p; r = s2.row0 + (k - s0.len - s1.len); }
    v[j] = (__bf16)src[(size_t)r * N + n];
  }
  *(bf16x8*)(dst + (size_t)f * 8) = v;
}

struct Params {
  const float *h_i, *input_t, *eps_inf, *eps_prior;
  const float *b_lstm, *b1, *b2, *b3, *b4, *b5, *b6, *b7, *b8, *b9;
  const float *alpha, *beta, *mu0;
  const __bf16* wpack;
  float* out;
};

// issue one gates half-chunk: group g2 ∈ {0,1} = gates {0,1} / {2,3};
// frag i = g_local*2 + hh; ntile = g*16 + hh*8 + w
__device__ __forceinline__ void issueG(bf16x8 (&wf)[4], const bf16x8* wgs, int w,
                                       int lane, int kt, int g2) {
#pragma unroll
  for (int i = 0; i < 4; ++i) {
    int g = g2 * 2 + (i >> 1), hh = i & 1;
    wf[i] = gld(wgs + ((size_t)((g * 16 + hh * 8 + w) * 14 + kt) << 6) + lane);
  }
}

__global__ __launch_bounds__(512) __attribute__((amdgpu_waves_per_eu(4, 4)))
void decoder_main(Params p) {
  __shared__ __align__(16) unsigned char act[ROWS * ACT_STRIDE + 16];  // ~52 KB
  __shared__ float inten[STEPS * ROWS];                                // 2.5 KB

  const int tid = threadIdx.x;
  const int w = tid >> 6;        // 0..7
  const int lane = tid & 63;
  const int ln16 = lane & 15;
  const int rsub = (lane >> 4) << 2;
  const int r0 = blockIdx.x * ROWS;

  for (int i = tid; i < (ROWS * ACT_STRIDE + 16) / 4; i += 512)
    ((unsigned int*)act)[i] = 0u;
  __syncthreads();
  // stage h_i bf16 into C_C (consumed by the startup folds only)
  for (int i = tid; i < ROWS * 256; i += 512) {
    int row = i >> 8, col = i & 255;
    *(__bf16*)(act + act_off(row, C_C + col)) =
        (__bf16)p.h_i[(size_t)(r0 + row) * HDIM + col];
  }
  {
    float ab = p.alpha[0] * p.beta[0], mu = p.mu0[0];
    for (int t = tid; t < ROWS * STEPS; t += 512) {
      int row = t & (ROWS - 1), j = t >> 4;
      const float* tp = p.input_t + (size_t)(r0 + row) * TDIM;
      float tc = tp[j + 3];
      float s = 0.f;
      for (int idx = 0; idx < j + 3; ++idx) s += __expf(tp[idx] - tc);
      inten[j * ROWS + row] = mu + ab * s;
    }
  }
  __syncthreads();

  const __bf16* W = p.wpack;
  const bf16x8* wgs = (const bf16x8*)(W + PW_GS);
  const bf16x8* wghi = (const bf16x8*)(W + PW_GHI);
  const bf16x8* w1p = (const bf16x8*)(W + PW_W1);
  const bf16x8* w2p = (const bf16x8*)(W + PW_W2);
  const bf16x8* w3p = (const bf16x8*)(W + PW_W3);
  const bf16x8* w4s = (const bf16x8*)(W + PW_W4S);
  const bf16x8* w4h = (const bf16x8*)(W + PW_W4H);
  const bf16x8* w5p = (const bf16x8*)(W + PW_W5);
  const bf16x8* w6p = (const bf16x8*)(W + PW_W6);
  const bf16x8* w7s = (const bf16x8*)(W + PW_W7S);
  const bf16x8* w7h = (const bf16x8*)(W + PW_W7H);
  const bf16x8* w8p = (const bf16x8*)(W + PW_W8);
  const bf16x8* w9p = (const bf16x8*)(W + PW_W9);

  // ---- startup folds (plain C loads; latency uncritical) ----
  uint2 gbp[4][2];  // h_i@Wx_hi + b_lstm, packed bf16 per (gate, half)
  {
    f32x4 g4[4][2] = {};
#pragma unroll
    for (int kt = 0; kt < 8; ++kt) {
      bf16x8 a = aread(act, C_C + kt * 32, lane);
#pragma unroll
      for (int g = 0; g < 4; ++g)
#pragma unroll
        for (int hh = 0; hh < 2; ++hh) {
          bf16x8 b = wghi[((size_t)((g * 16 + hh * 8 + w) * 8 + kt)) * 64 + lane];
          g4[g][hh] = mfma16(a, b, g4[g][hh]);
        }
    }
#pragma unroll
    for (int g = 0; g < 4; ++g)
#pragma unroll
      for (int hh = 0; hh < 2; ++hh) {
        float bv = p.b_lstm[g * 256 + hh * 128 + w * 16 + ln16];
        gbp[g][hh].x = pk2(g4[g][hh][0] + bv, g4[g][hh][1] + bv);
        gbp[g][hh].y = pk2(g4[g][hh][2] + bv, g4[g][hh][3] + bv);
      }
  }
  // role params: waves 0-3 (inf/y side, n=w), waves 4-7 (prior side, n=w-4)
  const int nr = (w < 4) ? w : (w - 4);
  f32x4 foldv = {};            // w<4: h_i@w4h+b4 ; w>=4: h_i@w7h+b7
  bf16x8 wA[2], wB[2];         // w<4: w5,w6 ; w>=4: w8,w9
  float bA, bB;
  {
    const bf16x8* wph = (w < 4) ? w4h : w7h;
    const float* bbh = (w < 4) ? p.b4 : p.b7;
    f32x4 v = {};
#pragma unroll
    for (int kt = 0; kt < 8; ++kt)
      v = mfma16(aread(act, C_C + kt * 32, lane),
                 wph[(size_t)(nr * 8 + kt) * 64 + lane], v);
    float bv = bbh[nr * 16 + ln16];
#pragma unroll
    for (int r = 0; r < 4; ++r) foldv[r] = v[r] + bv;
    const bf16x8* wpa = (w < 4) ? w5p : w8p;
    const bf16x8* wpb = (w < 4) ? w6p : w9p;
#pragma unroll
    for (int kt = 0; kt < 2; ++kt) {
      wA[kt] = wpa[(size_t)(nr * 2 + kt) * 64 + lane];
      wB[kt] = wpb[(size_t)(nr * 2 + kt) * 64 + lane];
    }
    bA = ((w < 4) ? p.b5 : p.b8)[nr * 16 + ln16];
    bB = ((w < 4) ? p.b6 : p.b9)[nr * 16 + ln16];
  }
  const float bi = p.b_lstm[0];  // placeholder suppressed; real biases in gbp
  (void)bi;
  const float bv1 = p.b1[w * 16 + ln16];
  float bv2 = 0.f, bv3 = 0.f;
  if (w < 4) {
    bv2 = p.b2[w * 16 + ln16];          // tile w
    bv3 = p.b3[w * 16 + ln16];
  }
  float bv2b = 0.f, bv3b = 0.f;
  if (w < 4) {
    bv2b = p.b2[(4 + w) * 16 + ln16];   // tile 4+w
    bv3b = p.b3[(4 + w) * 16 + ln16];
  }
  f32x4 c_st[2] = {};  // per wave: halves hh=0,1 at col hh*128 + w*16
  __syncthreads();

  float* outy = p.out;
  float* outm = p.out + (size_t)BDIM * STEPS * FDIM;
  float* outl = outm + (size_t)BDIM * STEPS * ZDIM;
  float* outz = outl + (size_t)BDIM * STEPS * ZDIM;
  float* outzp = outz + (size_t)BDIM * STEPS * ZDIM;

  // gates rotating chunk buffers (persist across barriers in registers)
  bf16x8 X[4], Y[4];
  issueG(X, wgs, w, lane, 0, 0);
  issueG(Y, wgs, w, lane, 0, 1);

  for (int j = 0; j < STEPS; ++j) {
    const int yW = (j & 1) ? C_Y1 : C_Y0, yR = (j & 1) ? C_Y0 : C_Y1;
    const int hW = (j & 1) ? C_H1 : C_H0, hR = (j & 1) ? C_H0 : C_H1;

    // ---- A: gates = [z|yp|h]@Wgs + gbp-fold; X/Y rotating chunks ----
    {
      f32x4 acc[4][2];
#pragma unroll
      for (int g = 0; g < 4; ++g)
#pragma unroll
        for (int hh = 0; hh < 2; ++hh) {
          acc[g][hh][0] = upkf(gbp[g][hh].x, 0);
          acc[g][hh][1] = upkf(gbp[g][hh].x, 1);
          acc[g][hh][2] = upkf(gbp[g][hh].y, 0);
          acc[g][hh][3] = upkf(gbp[g][hh].y, 1);
        }
#pragma unroll
      for (int kt = 0; kt < 14; ++kt) {
        int col = (kt < 2) ? (C_Z + kt * 32)
                           : (kt < 6) ? (yR + (kt - 2) * 32) : (hR + (kt - 6) * 32);
        bf16x8 a = aread(act, col, lane);
        VMW(4);  // X(kt) complete (Y(kt) may be outstanding)
#pragma unroll
        for (int i = 0; i < 4; ++i)
          acc[(i >> 1)][i & 1] = mfma16(a, X[i], acc[(i >> 1)][i & 1]);
        SB();
        if (kt + 1 < 14) issueG(X, wgs, w, lane, kt + 1, 0);
        if (kt + 1 < 14) { VMW(4); } else { VMW(0); }  // Y(kt) complete
#pragma unroll
        for (int i = 0; i < 4; ++i)
          acc[2 + (i >> 1)][i & 1] = mfma16(a, Y[i], acc[2 + (i >> 1)][i & 1]);
        SB();
        if (kt + 1 < 14) issueG(Y, wgs, w, lane, kt + 1, 1);
      }
#pragma unroll
      for (int hh = 0; hh < 2; ++hh) {
        int colc = hh * 128 + w * 16 + ln16;
#pragma unroll
        for (int r = 0; r < 4; ++r) {
          int row = rsub + r;
          float ig = sigm(acc[0][hh][r]);
          float fg = sigm(acc[1][hh][r]);
          float gg = tanh_f(acc[2][hh][r]);
          float og = sigm(acc[3][hh][r]);
          float cn = fg * c_st[hh][r] + ig * gg;
          float hn = og * tanh_f(cn);
          c_st[hh][r] = inten[j * ROWS + row] * cn;
          *(__bf16*)(act + act_off(row, C_C + colc)) = (__bf16)cn;
          *(__bf16*)(act + act_off(row, hW + colc)) = (__bf16)hn;
        }
      }
    }
    wg_barrier();

    // ---- B: y1 = relu(h@w1+b1), all 8 waves, tile n=w ----
    {
      bf16x8 wf[8];
#pragma unroll
      for (int kt = 0; kt < 8; ++kt)
        wf[kt] = gld(w1p + (size_t)(w * 8 + kt) * 64 + lane);
      VMW(0);
      f32x4 v = {};
#pragma unroll
      for (int kt = 0; kt < 8; ++kt)
        v = mfma16(aread(act, hW + kt * 32, lane), wf[kt], v);
      st16(act, C_T0 + w * 16 + ln16, rsub, v, bv1);
    }
    wg_barrier();

    // ---- C: w0-3 y2 (tiles w, 4+w); w4-7 hzp full-K -> C_HZP ----
    {
      if (w < 4) {
        bf16x8 wf[8];
#pragma unroll
        for (int kt = 0; kt < 4; ++kt) {
          wf[kt] = gld(w2p + (size_t)(w * 4 + kt) * 64 + lane);
          wf[4 + kt] = gld(w2p + (size_t)((4 + w) * 4 + kt) * 64 + lane);
        }
        VMW(0);
        f32x4 v0 = {}, v1 = {};
#pragma unroll
        for (int kt = 0; kt < 4; ++kt) {
          bf16x8 a = aread(act, C_T0 + kt * 32, lane);
          v0 = mfma16(a, wf[kt], v0);
          v1 = mfma16(a, wf[4 + kt], v1);
        }
        st16(act, C_T1 + w * 16 + ln16, rsub, v0, bv2);
        st16(act, C_T1 + (4 + w) * 16 + ln16, rsub, v1, bv2b);
      } else {
        bf16x8 wf[12];
#pragma unroll
        for (int kt = 0; kt < 12; ++kt)
          wf[kt] = gld(w7s + (size_t)(nr * 12 + kt) * 64 + lane);
        VMW(0);
        f32x4 v = {};
#pragma unroll
        for (int kt = 0; kt < 12; ++kt) {
          int col = (kt < 8) ? (C_C + kt * 32) : (yR + (kt - 8) * 32);
          v = mfma16(aread(act, col, lane), wf[kt], v);
        }
#pragma unroll
        for (int r = 0; r < 4; ++r)
          *(__bf16*)(act + act_off(rsub + r, C_HZP + nr * 16 + ln16)) =
              (__bf16)fmaxf(v[r] + foldv[r], 0.f);
      }
    }
    wg_barrier();

    // ---- D: w0-3 y3 -> yW + outy; w4-7 mean_p/lv_p + zp ----
    {
      if (w < 4) {
        bf16x8 wf[8];
#pragma unroll
        for (int kt = 0; kt < 4; ++kt) {
          wf[kt] = gld(w3p + (size_t)(w * 4 + kt) * 64 + lane);
          wf[4 + kt] = gld(w3p + (size_t)((4 + w) * 4 + kt) * 64 + lane);
        }
        VMW(0);
        f32x4 v0 = {}, v1 = {};
#pragma unroll
        for (int kt = 0; kt < 4; ++kt) {
          bf16x8 a = aread(act, C_T1 + kt * 32, lane);
          v0 = mfma16(a, wf[kt], v0);
          v1 = mfma16(a, wf[4 + kt], v1);
        }
#pragma unroll
        for (int r = 0; r < 4; ++r) {
          int row = rsub + r;
          float y0 = fmaxf(v0[r] + bv3, 0.f);
          float y1 = fmaxf(v1[r] + bv3b, 0.f);
          *(__bf16*)(act + act_off(row, yW + w * 16 + ln16)) = (__bf16)y0;
          *(__bf16*)(act + act_off(row, yW + 64 + w * 16 + ln16)) = (__bf16)y1;
          size_t ob = ((size_t)(r0 + row) * STEPS + j) * FDIM;
          __builtin_nontemporal_store(y0, outy + ob + w * 16 + ln16);
          __builtin_nontemporal_store(y1, outy + ob + 64 + w * 16 + ln16);
        }
      } else {
        float ep[4];
#pragma unroll
        for (int r = 0; r < 4; ++r)
          ep[r] = p.eps_prior[((size_t)j * BDIM + r0 + rsub + r) * ZDIM +
                              nr * 16 + ln16];
        f32x4 vm = {}, vl = {};
#pragma unroll
        for (int kt = 0; kt < 2; ++kt) {
          bf16x8 a = aread(act, C_HZP + kt * 32, lane);
          vm = mfma16(a, wA[kt], vm);
          vl = mfma16(a, wB[kt], vl);
        }
#pragma unroll
        for (int r = 0; r < 4; ++r) {
          float mp = fmaxf(vm[r] + bA, 0.f), lp = fmaxf(vl[r] + bB, 0.f);
          float zp = mp + ep[r] * __expf(0.5f * lp);
          __builtin_nontemporal_store(
              zp, outzp + ((size_t)(r0 + rsub + r) * STEPS + j) * ZDIM +
                      nr * 16 + ln16);
        }
      }
    }
    wg_barrier();

    // ---- E: w0-3 hz full-K ([c|y|yp]@w4s) -> C_HZ; also load ei ----
    float ei[4];
    if (w < 4) {
      bf16x8 wf[16];
#pragma unroll
      for (int kt = 0; kt < 16; ++kt)
        wf[kt] = gld(w4s + (size_t)(nr * 16 + kt) * 64 + lane);
#pragma unroll
      for (int r = 0; r < 4; ++r)
        ei[r] = p.eps_inf[((size_t)j * BDIM + r0 + rsub + r) * ZDIM +
                          nr * 16 + ln16];
      VMW(0);
      f32x4 v = {};
#pragma unroll
      for (int kt = 0; kt < 16; ++kt) {
        int col = (kt < 8) ? (C_C + kt * 32)
                           : (kt < 12) ? (yW + (kt - 8) * 32) : (yR + (kt - 12) * 32);
        v = mfma16(aread(act, col, lane), wf[kt], v);
      }
#pragma unroll
      for (int r = 0; r < 4; ++r)
        *(__bf16*)(act + act_off(rsub + r, C_HZ + nr * 16 + ln16)) =
            (__bf16)fmaxf(v[r] + foldv[r], 0.f);
    }
    wg_barrier();

    // ---- F: w0-3 mean/lv + z -> outputs + C_Z; all waves refill X/Y ----
    if (w < 4) {
      f32x4 vm = {}, vl = {};
#pragma unroll
      for (int kt = 0; kt < 2; ++kt) {
        bf16x8 a = aread(act, C_HZ + kt * 32, lane);
        vm = mfma16(a, wA[kt], vm);
        vl = mfma16(a, wB[kt], vl);
      }
#pragma unroll
      for (int r = 0; r < 4; ++r) {
        int row = rsub + r, col = nr * 16 + ln16;
        float m = fmaxf(vm[r] + bA, 0.f), l = fmaxf(vl[r] + bB, 0.f);
        float zn = m + ei[r] * __expf(0.5f * l);
        size_t ob = ((size_t)(r0 + row) * STEPS + j) * ZDIM + col;
        __builtin_nontemporal_store(m, outm + ob);
        __builtin_nontemporal_store(l, outl + ob);
        __builtin_nontemporal_store(zn, outz + ob);
        *(__bf16*)(act + act_off(row, C_Z + col)) = (__bf16)zn;
      }
    }
    issueG(X, wgs, w, lane, 0, 0);  // next step (in flight across barrier)
    issueG(Y, wgs, w, lane, 0, 1);
    wg_barrier();
  }
}

extern "C" void kernel_launch(void* const* d_in, const int* in_sizes, int n_in,
                              void* d_out, int out_size, void* d_ws, size_t ws_size,
                              hipStream_t stream) {
  const float* h_i = (const float*)d_in[0];
  const float* input_t = (const float*)d_in[1];
  const float* eps_inf = (const float*)d_in[2];
  const float* eps_prior = (const float*)d_in[3];
  const float* Wx = (const float*)d_in[4];
  const float* Wh = (const float*)d_in[5];
  const float* b_lstm = (const float*)d_in[6];
  const float* w1 = (const float*)d_in[7];  const float* b1 = (const float*)d_in[8];
  const float* w2 = (const float*)d_in[9];  const float* b2 = (const float*)d_in[10];
  const float* w3 = (const float*)d_in[11]; const float* b3 = (const float*)d_in[12];
  const float* w4 = (const float*)d_in[13]; const float* b4 = (const float*)d_in[14];
  const float* w5 = (const float*)d_in[15]; const float* b5 = (const float*)d_in[16];
  const float* w6 = (const float*)d_in[17]; const float* b6 = (const float*)d_in[18];
  const float* w7 = (const float*)d_in[19]; const float* b7 = (const float*)d_in[20];
  const float* w8 = (const float*)d_in[21]; const float* b8 = (const float*)d_in[22];
  const float* w9 = (const float*)d_in[23]; const float* b9 = (const float*)d_in[24];
  const float* alpha = (const float*)d_in[25];
  const float* beta = (const float*)d_in[26];
  const float* mu0 = (const float*)d_in[27];
  __bf16* ws = (__bf16*)d_ws;

  auto S = [](const float* ptr, int row0, int len) {
    PSeg s; s.p = ptr; s.row0 = row0; s.len = len; return s;
  };
  PSeg Zs; Zs.p = nullptr; Zs.row0 = 0; Zs.len = 0;
  auto L = [&](PSeg a, PSeg b, PSeg c, int K, int N, unsigned off) {
    int total = (K / 32) * (N / 16) * 64;
    pack_w<<<(total + 255) / 256, 256, 0, stream>>>(a, b, c, K, N, ws + off);
  };
  L(S(Wx, 0, 64), S(Wx, 320, 128), S(Wh, 0, 256), 448, 1024, PW_GS);  // [z|yp|h]
  L(S(Wx, 64, 256), Zs, Zs, 256, 1024, PW_GHI);
  L(S(w1, 0, 256), Zs, Zs, 256, 128, PW_W1);
  L(S(w2, 0, 128), Zs, Zs, 128, 128, PW_W2);
  L(S(w3, 0, 128), Zs, Zs, 128, 128, PW_W3);
  L(S(w4, 256, 512), Zs, Zs, 512, 64, PW_W4S);  // [c|y|yp]
  L(S(w4, 0, 256), Zs, Zs, 256, 64, PW_W4H);
  L(S(w5, 0, 64), Zs, Zs, 64, 64, PW_W5);
  L(S(w6, 0, 64), Zs, Zs, 64, 64, PW_W6);
  L(S(w7, 256, 384), Zs, Zs, 384, 64, PW_W7S);  // [c|yp]
  L(S(w7, 0, 256), Zs, Zs, 256, 64, PW_W7H);
  L(S(w8, 0, 64), Zs, Zs, 64, 64, PW_W8);
  L(S(w9, 0, 64), Zs, Zs, 64, 64, PW_W9);

  Params p;
  p.h_i = h_i; p.input_t = input_t; p.eps_inf = eps_inf; p.eps_prior = eps_prior;
  p.b_lstm = b_lstm; p.b1 = b1; p.b2 = b2; p.b3 = b3; p.b4 = b4; p.b5 = b5;
  p.b6 = b6; p.b7 = b7; p.b8 = b8; p.b9 = b9;
  p.alpha = alpha; p.beta = beta; p.mu0 = mu0;
  p.wpack = ws;
  p.out = (float*)d_out;

  decoder_main<<<512, 512, 0, stream>>>(p);
}

// Round 13
// 3836.242 us; speedup vs baseline: 1.5622x; 1.1828x over previous
//
#include <hip/hip_runtime.h>

// ---------------------------------------------------------------------------
// Fused decoder R13: B=8192 x 40 steps, 1 WG (512 thr, 8 waves) per 32 rows,
// grid=256, waves_per_eu(2,2) -> 128 VGPR. Gates GEMM (K=704, 22 k-tiles)
// SPREAD ACROSS THE STEP: phase A holds only the z-part (2 kt) + pointwise;
// h/h_i/yp k-tiles are appended to phases B-F as soon as their inputs exist
// (h after A, y after D, h_i anytime). Continuous weight stream, short
// critical chains, tail-phase compute fill. Tail bodies = R4-proven.
// ---------------------------------------------------------------------------

#define BDIM  8192
#define HDIM  256
#define FDIM  128
#define ZDIM  64
#define TDIM  43
#define STEPS 40

typedef __attribute__((ext_vector_type(8))) __bf16 bf16x8;
typedef __attribute__((ext_vector_type(4))) float  f32x4;

// act: 32 rows x 1728 bf16 cols, stride 3504B (876 dw == 12 mod 32), +16B/8rows
#define ACT_STRIDE 3504
#define C_Z   0      // z (64)
#define C_HI  64     // h_i (256, permanent)
#define C_Y0  320    // y parity 0 (128)
#define C_Y1  448    // y parity 1 (128)
#define C_H0  576    // h parity 0 (256)
#define C_H1  832    // h parity 1 (256)
#define C_C   1088   // c_new (256)
#define C_T0  1344   // y1 (128)
#define C_T1  1472   // y2 (128)
#define C_HZ  1600   // hz (64)
#define C_HZP 1664   // hzp (64)  -> 1728 cols

// packed-weight offsets in __bf16 elements
#define PW_GS  0u         // gates [z|h_i|yp|h] K=704 N=1024 (KT=22)
#define PW_W1  720896u    // K=256 N=128 (KT=8)
#define PW_W2  753664u    // K=128 N=128 (KT=4)
#define PW_W3  770048u    // K=128 N=128 (KT=4)
#define PW_W4S 786432u    // w4 rows 256:768 [c|y|yp] K=512 N=64 (KT=16)
#define PW_W4H 819200u    // w4 rows 0:256 K=256 N=64 (KT=8)
#define PW_W5  835584u    // K=64 N=64 (KT=2)
#define PW_W6  839680u
#define PW_W7S 843776u    // w7 rows 256:640 [c|yp] K=384 N=64 (KT=12)
#define PW_W7H 868352u    // w7 rows 0:256 K=256 N=64 (KT=8)
#define PW_W8  884736u
#define PW_W9  888832u

__device__ __forceinline__ int act_off(int row, int col) {
  return row * ACT_STRIDE + ((row >> 3) << 4) + (col << 1);
}
__device__ __forceinline__ f32x4 mfma16(bf16x8 a, bf16x8 b, f32x4 c) {
  return __builtin_amdgcn_mfma_f32_16x16x32_bf16(a, b, c, 0, 0, 0);
}
__device__ __forceinline__ float sigm(float x) { return 1.f / (1.f + __expf(-x)); }
__device__ __forceinline__ float tanh_f(float x) {
  float t = __expf(-2.f * fabsf(x));
  float r = (1.f - t) / (1.f + t);
  return x < 0.f ? -r : r;
}
__device__ __forceinline__ void wg_barrier() {
  asm volatile("s_waitcnt lgkmcnt(0)" ::: "memory");
  __builtin_amdgcn_s_barrier();
  __builtin_amdgcn_sched_barrier(0);
}
// A-fragment read: lane l holds A[mt*16 + (l&15)][k=(l>>4)*8+j]
__device__ __forceinline__ bf16x8 aread16(const unsigned char* a, int mt, int col,
                                          int lane) {
  return *(const bf16x8*)(a + act_off(mt * 16 + (lane & 15), col + ((lane >> 4) << 3)));
}
__device__ __forceinline__ void st16(unsigned char* a, int col, int mt, int rsub,
                                     f32x4 v, float bv) {
#pragma unroll
  for (int r = 0; r < 4; ++r)
    *(__bf16*)(a + act_off(mt * 16 + rsub + r, col)) = (__bf16)fmaxf(v[r] + bv, 0.f);
}

// ---------------------------------------------------------------------------
// Packer (R4-proven): up to 3 K-stacked segments -> 16-wide B-fragments
// frag f=(nt*KT+kt)*64+lane holds W[kt*32+(lane>>4)*8+j][nt*16+(lane&15)]
// ---------------------------------------------------------------------------
struct PSeg { const float* p; int row0; int len; };

__global__ __launch_bounds__(256) void pack_w(PSeg s0, PSeg s1, PSeg s2,
                                              int K, int N, __bf16* __restrict__ dst) {
  int f = blockIdx.x * 256 + threadIdx.x;
  int KT = K >> 5;
  int total = KT * (N >> 4) * 64;
  if (f >= total) return;
  int lane = f & 63;
  int tile = f >> 6;
  int kt = tile % KT;
  int nt = tile / KT;
  int k0 = kt * 32 + ((lane >> 4) << 3);
  int n = (nt << 4) + (lane & 15);
  bf16x8 v;
#pragma unroll
  for (int j = 0; j < 8; ++j) {
    int k = k0 + j;
    const float* src;
    int r;
    if (k < s0.len) { src = s0.p; r = s0.row0 + k; }
    else if (k < s0.len + s1.len) { src = s1.p; r = s1.row0 + (k - s0.len); }
    else { src = s2.p; r = s2.row0 + (k - s0.len - s1.len); }
    v[j] = (__bf16)src[(size_t)r * N + n];
  }
  *(bf16x8*)(dst + (size_t)f * 8) = v;
}

struct Params {
  const float *h_i, *input_t, *eps_inf, *eps_prior;
  const float *b_lstm, *b1, *b2, *b3, *b4, *b5, *b6, *b7, *b8, *b9;
  const float *alpha, *beta, *mu0;
  const __bf16* wpack;
  float* out;
};

__global__ __launch_bounds__(512) __attribute__((amdgpu_waves_per_eu(2, 2)))
void decoder_main(Params p) {
  __shared__ __align__(16) unsigned char act[32 * ACT_STRIDE];  // 112128 B
  __shared__ float inten[STEPS * 32];                           // 5120 B

  const int tid = threadIdx.x;
  const int w = tid >> 6;        // 0..7
  const int lane = tid & 63;
  const int ln16 = lane & 15;
  const int rsub = (lane >> 4) << 2;
  const int r0 = blockIdx.x * 32;

  for (int i = tid; i < (32 * ACT_STRIDE) / 4; i += 512) ((unsigned int*)act)[i] = 0u;
  __syncthreads();
  for (int i = tid; i < 32 * 256; i += 512) {
    int row = i >> 8, col = i & 255;
    *(__bf16*)(act + act_off(row, C_HI + col)) =
        (__bf16)p.h_i[(size_t)(r0 + row) * HDIM + col];
  }
  {
    float ab = p.alpha[0] * p.beta[0], mu = p.mu0[0];
    for (int t = tid; t < 32 * STEPS; t += 512) {
      int row = t & 31, j = t >> 5;
      const float* tp = p.input_t + (size_t)(r0 + row) * TDIM;
      float tc = tp[j + 3];
      float s = 0.f;
      for (int idx = 0; idx < j + 3; ++idx) s += __expf(tp[idx] - tc);
      inten[j * 32 + row] = mu + ab * s;
    }
  }
  __syncthreads();

  const __bf16* W = p.wpack;
  const bf16x8* wgs = (const bf16x8*)(W + PW_GS);
  const bf16x8* w1p = (const bf16x8*)(W + PW_W1);
  const bf16x8* w2p = (const bf16x8*)(W + PW_W2);
  const bf16x8* w3p = (const bf16x8*)(W + PW_W3);
  const bf16x8* w4s = (const bf16x8*)(W + PW_W4S);
  const bf16x8* w4h = (const bf16x8*)(W + PW_W4H);
  const bf16x8* w5p = (const bf16x8*)(W + PW_W5);
  const bf16x8* w6p = (const bf16x8*)(W + PW_W6);
  const bf16x8* w7s = (const bf16x8*)(W + PW_W7S);
  const bf16x8* w7h = (const bf16x8*)(W + PW_W7H);
  const bf16x8* w8p = (const bf16x8*)(W + PW_W8);
  const bf16x8* w9p = (const bf16x8*)(W + PW_W9);

  const int n2 = w & 3, m2 = w >> 2;
  // startup folds: h_i@w4h+b4 -> b4f, h_i@w7h+b7 -> b7f (per-wave (n2,m2))
  f32x4 b4f = {}, b7f = {};
  {
    f32x4 v4 = {}, v7 = {};
#pragma unroll
    for (int kt = 0; kt < 8; ++kt) {
      bf16x8 a = aread16(act, m2, C_HI + kt * 32, lane);
      v4 = mfma16(a, w4h[(size_t)(n2 * 8 + kt) * 64 + lane], v4);
      v7 = mfma16(a, w7h[(size_t)(n2 * 8 + kt) * 64 + lane], v7);
    }
    float b4v = p.b4[n2 * 16 + ln16], b7v = p.b7[n2 * 16 + ln16];
#pragma unroll
    for (int r = 0; r < 4; ++r) { b4f[r] = v4[r] + b4v; b7f[r] = v7[r] + b7v; }
  }
  // bias hoists
  float bg4[4][2];
#pragma unroll
  for (int g = 0; g < 4; ++g)
#pragma unroll
    for (int t = 0; t < 2; ++t)
      bg4[g][t] = p.b_lstm[g * 256 + (w * 2 + t) * 16 + ln16];
  const float bv1 = p.b1[w * 16 + ln16];
  const float bv2 = p.b2[w * 16 + ln16];
  const float bv3 = p.b3[w * 16 + ln16];
  const float b5v = p.b5[n2 * 16 + ln16];
  const float b6v = p.b6[n2 * 16 + ln16];
  const float b8v = p.b8[n2 * 16 + ln16];
  const float b9v = p.b9[n2 * 16 + ln16];
  f32x4 c_st[2][2] = {};  // [t][mt]
  __syncthreads();

  float* outy = p.out;
  float* outm = p.out + (size_t)BDIM * STEPS * FDIM;
  float* outl = outm + (size_t)BDIM * STEPS * ZDIM;
  float* outz = outl + (size_t)BDIM * STEPS * ZDIM;
  float* outzp = outz + (size_t)BDIM * STEPS * ZDIM;

  // gates accumulator, persistent across phases: [gate][ntile-half][mtile]
  f32x4 acc[4][2][2] = {};

  // one gates k-tile: kt 0-1=z, 2-9=h_i, 10-13=y(ycol), 14-21=h(hcol)
#define GCHUNK(KT_, YCOL_, HCOL_)                                              \
  do {                                                                         \
    int col_ = ((KT_) < 2) ? (C_Z + (KT_)*32)                                  \
               : ((KT_) < 10) ? (C_HI + ((KT_)-2) * 32)                        \
               : ((KT_) < 14) ? ((YCOL_) + ((KT_)-10) * 32)                    \
                              : ((HCOL_) + ((KT_)-14) * 32);                   \
    bf16x8 a0_ = aread16(act, 0, col_, lane);                                  \
    bf16x8 a1_ = aread16(act, 1, col_, lane);                                  \
    _Pragma("unroll") for (int g_ = 0; g_ < 4; ++g_) {                         \
      _Pragma("unroll") for (int t_ = 0; t_ < 2; ++t_) {                       \
        bf16x8 b_ = wgs[((size_t)((g_ * 16 + w * 2 + t_) * 22 + (KT_))) * 64 + \
                        lane];                                                 \
        acc[g_][t_][0] = mfma16(a0_, b_, acc[g_][t_][0]);                      \
        acc[g_][t_][1] = mfma16(a1_, b_, acc[g_][t_][1]);                      \
      }                                                                        \
    }                                                                          \
  } while (0)

  // prologue: accumulate gates(0) kt 2..21 (h_i real; y/h/z buffers zeroed)
#pragma unroll 2
  for (int kt = 2; kt < 22; ++kt) GCHUNK(kt, C_Y1, C_H1);

  for (int j = 0; j < STEPS; ++j) {
    const int yW = (j & 1) ? C_Y1 : C_Y0, yR = (j & 1) ? C_Y0 : C_Y1;
    const int hW = (j & 1) ? C_H1 : C_H0;

    // ---- A: z-part k-tiles + LSTM pointwise -> C_C, hW ----
    GCHUNK(0, yW, hW);
    GCHUNK(1, yW, hW);
#pragma unroll
    for (int t = 0; t < 2; ++t) {
      int colc = (w * 2 + t) * 16 + ln16;
#pragma unroll
      for (int mt = 0; mt < 2; ++mt)
#pragma unroll
        for (int r = 0; r < 4; ++r) {
          int row = mt * 16 + rsub + r;
          float ig = sigm(acc[0][t][mt][r] + bg4[0][t]);
          float fg = sigm(acc[1][t][mt][r] + bg4[1][t]);
          float gg = tanh_f(acc[2][t][mt][r] + bg4[2][t]);
          float og = sigm(acc[3][t][mt][r] + bg4[3][t]);
          float cn = fg * c_st[t][mt][r] + ig * gg;
          float hn = og * tanh_f(cn);
          c_st[t][mt][r] = inten[j * 32 + row] * cn;
          *(__bf16*)(act + act_off(row, C_C + colc)) = (__bf16)cn;
          *(__bf16*)(act + act_off(row, hW + colc)) = (__bf16)hn;
        }
    }
    // reset acc for gates(j+1)
#pragma unroll
    for (int g = 0; g < 4; ++g)
#pragma unroll
      for (int t = 0; t < 2; ++t)
#pragma unroll
        for (int mt = 0; mt < 2; ++mt) acc[g][t][mt] = (f32x4){0.f, 0.f, 0.f, 0.f};
    wg_barrier();

    // ---- B: y1 = relu(h@w1+b1) -> C_T0 ; hzp=[c|yR]@w7s -> C_HZP ;
    //         + gates(j+1) kt 14,15 (h), 2,3 (h_i) ----
    {
      bf16x8 wf[8];
#pragma unroll
      for (int kt = 0; kt < 8; ++kt) wf[kt] = w1p[(size_t)(w * 8 + kt) * 64 + lane];
      f32x4 a0 = {}, a1 = {};
#pragma unroll
      for (int kt = 0; kt < 8; ++kt) {
        a0 = mfma16(aread16(act, 0, hW + kt * 32, lane), wf[kt], a0);
        a1 = mfma16(aread16(act, 1, hW + kt * 32, lane), wf[kt], a1);
      }
      st16(act, C_T0 + w * 16 + ln16, 0, rsub, a0, bv1);
      st16(act, C_T0 + w * 16 + ln16, 1, rsub, a1, bv1);
    }
    {
      bf16x8 wf[12];
#pragma unroll
      for (int kt = 0; kt < 12; ++kt) wf[kt] = w7s[(size_t)(n2 * 12 + kt) * 64 + lane];
      f32x4 v = {};
#pragma unroll
      for (int kt = 0; kt < 12; ++kt) {
        int col = (kt < 8) ? (C_C + kt * 32) : (yR + (kt - 8) * 32);
        v = mfma16(aread16(act, m2, col, lane), wf[kt], v);
      }
#pragma unroll
      for (int r = 0; r < 4; ++r)
        *(__bf16*)(act + act_off(m2 * 16 + rsub + r, C_HZP + n2 * 16 + ln16)) =
            (__bf16)fmaxf(v[r] + b7f[r], 0.f);
    }
    GCHUNK(14, yW, hW);
    GCHUNK(15, yW, hW);
    GCHUNK(2, yW, hW);
    GCHUNK(3, yW, hW);
    wg_barrier();

    // ---- C: y2 -> C_T1 ; mean_p/lv_p + zp store ; + kt 16,17,4,5 ----
    {
      bf16x8 wf[4];
#pragma unroll
      for (int kt = 0; kt < 4; ++kt) wf[kt] = w2p[(size_t)(w * 4 + kt) * 64 + lane];
      f32x4 a0 = {}, a1 = {};
#pragma unroll
      for (int kt = 0; kt < 4; ++kt) {
        a0 = mfma16(aread16(act, 0, C_T0 + kt * 32, lane), wf[kt], a0);
        a1 = mfma16(aread16(act, 1, C_T0 + kt * 32, lane), wf[kt], a1);
      }
      st16(act, C_T1 + w * 16 + ln16, 0, rsub, a0, bv2);
      st16(act, C_T1 + w * 16 + ln16, 1, rsub, a1, bv2);
    }
    {
      bf16x8 wm[2], wl[2];
      float ep[4];
#pragma unroll
      for (int kt = 0; kt < 2; ++kt) {
        wm[kt] = w8p[(size_t)(n2 * 2 + kt) * 64 + lane];
        wl[kt] = w9p[(size_t)(n2 * 2 + kt) * 64 + lane];
      }
#pragma unroll
      for (int r = 0; r < 4; ++r)
        ep[r] = p.eps_prior[((size_t)j * BDIM + r0 + m2 * 16 + rsub + r) * ZDIM +
                            n2 * 16 + ln16];
      f32x4 vm = {}, vl = {};
#pragma unroll
      for (int kt = 0; kt < 2; ++kt) {
        bf16x8 a = aread16(act, m2, C_HZP + kt * 32, lane);
        vm = mfma16(a, wm[kt], vm);
        vl = mfma16(a, wl[kt], vl);
      }
#pragma unroll
      for (int r = 0; r < 4; ++r) {
        float mp = fmaxf(vm[r] + b8v, 0.f), lp = fmaxf(vl[r] + b9v, 0.f);
        float zp = mp + ep[r] * __expf(0.5f * lp);
        __builtin_nontemporal_store(
            zp, outzp + ((size_t)(r0 + m2 * 16 + rsub + r) * STEPS + j) * ZDIM +
                    n2 * 16 + ln16);
      }
    }
    GCHUNK(16, yW, hW);
    GCHUNK(17, yW, hW);
    GCHUNK(4, yW, hW);
    GCHUNK(5, yW, hW);
    wg_barrier();

    // ---- D: y3 -> yW + outy ; + kt 18,19,6,7 ----
    {
      bf16x8 wf[4];
#pragma unroll
      for (int kt = 0; kt < 4; ++kt) wf[kt] = w3p[(size_t)(w * 4 + kt) * 64 + lane];
      f32x4 a0 = {}, a1 = {};
#pragma unroll
      for (int kt = 0; kt < 4; ++kt) {
        a0 = mfma16(aread16(act, 0, C_T1 + kt * 32, lane), wf[kt], a0);
        a1 = mfma16(aread16(act, 1, C_T1 + kt * 32, lane), wf[kt], a1);
      }
#pragma unroll
      for (int mt = 0; mt < 2; ++mt) {
        f32x4 vv = mt ? a1 : a0;
#pragma unroll
        for (int r = 0; r < 4; ++r) {
          int row = mt * 16 + rsub + r;
          float yv = fmaxf(vv[r] + bv3, 0.f);
          *(__bf16*)(act + act_off(row, yW + w * 16 + ln16)) = (__bf16)yv;
          __builtin_nontemporal_store(
              yv, outy + ((size_t)(r0 + row) * STEPS + j) * FDIM + w * 16 + ln16);
        }
      }
    }
    GCHUNK(18, yW, hW);
    GCHUNK(19, yW, hW);
    GCHUNK(6, yW, hW);
    GCHUNK(7, yW, hW);
    wg_barrier();

    // ---- E: hz full [c|yW|yR]@w4s + b4f -> C_HZ ; + kt 20,21,8,9 ----
    {
      f32x4 v = {};
      {
        bf16x8 wf[8];
#pragma unroll
        for (int kt = 0; kt < 8; ++kt) wf[kt] = w4s[(size_t)(n2 * 16 + kt) * 64 + lane];
#pragma unroll
        for (int kt = 0; kt < 8; ++kt)
          v = mfma16(aread16(act, m2, C_C + kt * 32, lane), wf[kt], v);
      }
      {
        bf16x8 wf[8];
#pragma unroll
        for (int kt = 8; kt < 16; ++kt)
          wf[kt - 8] = w4s[(size_t)(n2 * 16 + kt) * 64 + lane];
#pragma unroll
        for (int kt = 8; kt < 16; ++kt) {
          int col = (kt < 12) ? (yW + (kt - 8) * 32) : (yR + (kt - 12) * 32);
          v = mfma16(aread16(act, m2, col, lane), wf[kt - 8], v);
        }
      }
#pragma unroll
      for (int r = 0; r < 4; ++r)
        *(__bf16*)(act + act_off(m2 * 16 + rsub + r, C_HZ + n2 * 16 + ln16)) =
            (__bf16)fmaxf(v[r] + b4f[r], 0.f);
    }
    GCHUNK(20, yW, hW);
    GCHUNK(21, yW, hW);
    GCHUNK(8, yW, hW);
    GCHUNK(9, yW, hW);
    wg_barrier();

    // ---- F: mean/lv + z -> outputs + C_Z ; + kt 10..13 (yp = yW) ----
    {
      bf16x8 wm[2], wl[2];
      float ei[4];
#pragma unroll
      for (int kt = 0; kt < 2; ++kt) {
        wm[kt] = w5p[(size_t)(n2 * 2 + kt) * 64 + lane];
        wl[kt] = w6p[(size_t)(n2 * 2 + kt) * 64 + lane];
      }
#pragma unroll
      for (int r = 0; r < 4; ++r)
        ei[r] = p.eps_inf[((size_t)j * BDIM + r0 + m2 * 16 + rsub + r) * ZDIM +
                          n2 * 16 + ln16];
      f32x4 vm = {}, vl = {};
#pragma unroll
      for (int kt = 0; kt < 2; ++kt) {
        bf16x8 a = aread16(act, m2, C_HZ + kt * 32, lane);
        vm = mfma16(a, wm[kt], vm);
        vl = mfma16(a, wl[kt], vl);
      }
#pragma unroll
      for (int r = 0; r < 4; ++r) {
        int row = m2 * 16 + rsub + r, col = n2 * 16 + ln16;
        float m = fmaxf(vm[r] + b5v, 0.f), l = fmaxf(vl[r] + b6v, 0.f);
        float zn = m + ei[r] * __expf(0.5f * l);
        size_t ob = ((size_t)(r0 + row) * STEPS + j) * ZDIM + col;
        __builtin_nontemporal_store(m, outm + ob);
        __builtin_nontemporal_store(l, outl + ob);
        __builtin_nontemporal_store(zn, outz + ob);
        *(__bf16*)(act + act_off(row, C_Z + col)) = (__bf16)zn;
      }
    }
    GCHUNK(10, yW, hW);
    GCHUNK(11, yW, hW);
    GCHUNK(12, yW, hW);
    GCHUNK(13, yW, hW);
    wg_barrier();
  }
#undef GCHUNK
}

extern "C" void kernel_launch(void* const* d_in, const int* in_sizes, int n_in,
                              void* d_out, int out_size, void* d_ws, size_t ws_size,
                              hipStream_t stream) {
  const float* h_i = (const float*)d_in[0];
  const float* input_t = (const float*)d_in[1];
  const float* eps_inf = (const float*)d_in[2];
  const float* eps_prior = (const float*)d_in[3];
  const float* Wx = (const float*)d_in[4];
  const float* Wh = (const float*)d_in[5];
  const float* b_lstm = (const float*)d_in[6];
  const float* w1 = (const float*)d_in[7];  const float* b1 = (const float*)d_in[8];
  const float* w2 = (const float*)d_in[9];  const float* b2 = (const float*)d_in[10];
  const float* w3 = (const float*)d_in[11]; const float* b3 = (const float*)d_in[12];
  const float* w4 = (const float*)d_in[13]; const float* b4 = (const float*)d_in[14];
  const float* w5 = (const float*)d_in[15]; const float* b5 = (const float*)d_in[16];
  const float* w6 = (const float*)d_in[17]; const float* b6 = (const float*)d_in[18];
  const float* w7 = (const float*)d_in[19]; const float* b7 = (const float*)d_in[20];
  const float* w8 = (const float*)d_in[21]; const float* b8 = (const float*)d_in[22];
  const float* w9 = (const float*)d_in[23]; const float* b9 = (const float*)d_in[24];
  const float* alpha = (const float*)d_in[25];
  const float* beta = (const float*)d_in[26];
  const float* mu0 = (const float*)d_in[27];
  __bf16* ws = (__bf16*)d_ws;

  auto S = [](const float* ptr, int row0, int len) {
    PSeg s; s.p = ptr; s.row0 = row0; s.len = len; return s;
  };
  PSeg Zs; Zs.p = nullptr; Zs.row0 = 0; Zs.len = 0;
  auto L = [&](PSeg a, PSeg b, PSeg c, int K, int N, unsigned off) {
    int total = (K / 32) * (N / 16) * 64;
    pack_w<<<(total + 255) / 256, 256, 0, stream>>>(a, b, c, K, N, ws + off);
  };
  L(S(Wx, 0, 448), S(Wh, 0, 256), Zs, 704, 1024, PW_GS);  // [z|h_i|yp|h]
  L(S(w1, 0, 256), Zs, Zs, 256, 128, PW_W1);
  L(S(w2, 0, 128), Zs, Zs, 128, 128, PW_W2);
  L(S(w3, 0, 128), Zs, Zs, 128, 128, PW_W3);
  L(S(w4, 256, 512), Zs, Zs, 512, 64, PW_W4S);  // [c|y|yp]
  L(S(w4, 0, 256), Zs, Zs, 256, 64, PW_W4H);
  L(S(w5, 0, 64), Zs, Zs, 64, 64, PW_W5);
  L(S(w6, 0, 64), Zs, Zs, 64, 64, PW_W6);
  L(S(w7, 256, 384), Zs, Zs, 384, 64, PW_W7S);  // [c|yp]
  L(S(w7, 0, 256), Zs, Zs, 256, 64, PW_W7H);
  L(S(w8, 0, 64), Zs, Zs, 64, 64, PW_W8);
  L(S(w9, 0, 64), Zs, Zs, 64, 64, PW_W9);

  Params p;
  p.h_i = h_i; p.input_t = input_t; p.eps_inf = eps_inf; p.eps_prior = eps_prior;
  p.b_lstm = b_lstm; p.b1 = b1; p.b2 = b2; p.b3 = b3; p.b4 = b4; p.b5 = b5;
  p.b6 = b6; p.b7 = b7; p.b8 = b8; p.b9 = b9;
  p.alpha = alpha; p.beta = beta; p.mu0 = mu0;
  p.wpack = ws;
  p.out = (float*)d_out;

  decoder_main<<<256, 512, 0, stream>>>(p);
}